// Round 6
// baseline (473.626 us; speedup 1.0000x reference)
//
#include <hip/hip_runtime.h>
#include <math.h>

#define E_DIM 1024
#define H_NUM 16
#define HD 64
#define B_NUM 2
#define T_LEN 2048

typedef unsigned short u16;
typedef short bf16x8 __attribute__((ext_vector_type(8)));
typedef float f32x4 __attribute__((ext_vector_type(4)));
typedef unsigned short u16x4 __attribute__((ext_vector_type(4)));
typedef unsigned short u16x8 __attribute__((ext_vector_type(8)));

#define MFMA16(a, b, c) __builtin_amdgcn_mfma_f32_16x16x32_bf16(a, b, c, 0, 0, 0)

__device__ __forceinline__ u16 f2bf(float f) {
    unsigned u = __float_as_uint(f);
    u += 0x7FFFu + ((u >> 16) & 1u);   // RNE
    return (u16)(u >> 16);
}
__device__ __forceinline__ float bf2f(u16 b) {
    return __uint_as_float(((unsigned)b) << 16);
}
// async global->LDS 16B copy. LDS dest must be wave-uniform base + lane*16.
__device__ __forceinline__ void gl_lds16(const void* g, void* l) {
    __builtin_amdgcn_global_load_lds(
        (const __attribute__((address_space(1))) unsigned int*)g,
        (__attribute__((address_space(3))) unsigned int*)l, 16, 0, 0);
}

// ---------------------------------------------------------------------------
// convert x (fp32 [4096][1024]) -> xh, xl bf16 hi/lo, same layout
// ---------------------------------------------------------------------------
__global__ __launch_bounds__(256) void convert_x_kernel(
    const float* __restrict__ x, u16* __restrict__ xh, u16* __restrict__ xl)
{
    int i = (blockIdx.x * 256 + threadIdx.x) * 4;
    float4 f = *(const float4*)&x[i];
    float fv[4] = {f.x, f.y, f.z, f.w};
    u16x4 h, l;
    #pragma unroll
    for (int j = 0; j < 4; j++) {
        u16 hi = f2bf(fv[j]);
        h[j] = hi;
        l[j] = f2bf(fv[j] - bf2f(hi));
    }
    *(u16x4*)&xh[i] = h;
    *(u16x4*)&xl[i] = l;
}

// ---------------------------------------------------------------------------
// convert Wq/Wk/Wv ([16][1024][64] each) -> wth/wtl [3072][1024] bf16,
// WT[col=m*1024+h*64+i][e] = Wm[h][e][i]   (transpose via LDS tile)
// ---------------------------------------------------------------------------
__global__ __launch_bounds__(256) void convert_w_kernel(
    const float* __restrict__ Wq, const float* __restrict__ Wk, const float* __restrict__ Wv,
    u16* __restrict__ wth, u16* __restrict__ wtl)
{
    const int bx = blockIdx.x;
    const int m = bx >> 8, h = (bx >> 4) & 15, e0 = (bx & 15) * 64;
    const float* W = (m == 0 ? Wq : (m == 1 ? Wk : Wv));

    __shared__ u16 Th[64][65];
    __shared__ u16 Tl[64][65];
    const int tid = threadIdx.x;

    #pragma unroll
    for (int j = 0; j < 16; j++) {
        int idx = j * 256 + tid;
        int e = idx >> 6, i = idx & 63;
        float f = W[((size_t)h * E_DIM + e0 + e) * HD + i];
        u16 hi = f2bf(f);
        Th[i][e] = hi;
        Tl[i][e] = f2bf(f - bf2f(hi));
    }
    __syncthreads();
    #pragma unroll
    for (int j = 0; j < 16; j++) {
        int idx = j * 256 + tid;
        int i = idx >> 6, e = idx & 63;
        size_t o = (size_t)(m * 1024 + h * 64 + i) * E_DIM + e0 + e;
        wth[o] = Th[i][e];
        wtl[o] = Tl[i][e];
    }
}

// ---------------------------------------------------------------------------
// convert Wo (fp32 [1024][1024]) -> wob bf16 same layout
// ---------------------------------------------------------------------------
__global__ __launch_bounds__(256) void convert_wo_kernel(
    const float* __restrict__ Wo, u16* __restrict__ wob)
{
    int i = (blockIdx.x * 256 + threadIdx.x) * 4;
    float4 f = *(const float4*)&Wo[i];
    float fv[4] = {f.x, f.y, f.z, f.w};
    u16x4 h;
    #pragma unroll
    for (int j = 0; j < 4; j++) h[j] = f2bf(fv[j]);
    *(u16x4*)&wob[i] = h;
}

// ---------------------------------------------------------------------------
// Fused QKV GEMM: 128(M) x 64(N) tiles, BK=32, grid (48,32)=1536 blocks.
// A (x) staged hi/lo in LDS; B (weights) frags loaded DIRECTLY global->VGPR
// (parallel L1/L2 pipe — offloads the LDS bottleneck). LDS 17.4 KB.
// ---------------------------------------------------------------------------
__global__ __launch_bounds__(256) void qkv_mfma_kernel(
    const u16* __restrict__ xh, const u16* __restrict__ xl,
    const u16* __restrict__ wth, const u16* __restrict__ wtl,
    u16* __restrict__ qh, u16* __restrict__ ql,
    u16* __restrict__ kh, u16* __restrict__ kl,
    u16* __restrict__ vt)
{
    const int bx = blockIdx.x;
    const int c0 = bx * 64;            // global col
    const int r0 = blockIdx.y * 128;   // global row
    const int m  = bx >> 4;            // 0=q 1=k 2=v
    const int h  = bx & 15;            // head
    const bool lo = (m != 2);

    // A staging 128x32 hi/lo = 8192 u16; v-transpose epilogue needs 8704.
    __shared__ __align__(16) u16 SM[8704];
    u16* Ah = SM;            // 4096
    u16* Al = SM + 4096;     // 4096

    const int tid = threadIdx.x;
    const int w = tid >> 6, lane = tid & 63;
    const int qd = lane >> 4, n16 = lane & 15;
    const int wr = w >> 1, wc = w & 1;   // rows wr*64..+63, cols wc*32..+31

    // per-lane B row bases (fixed): row = c0 + wc*32 + j*16 + n16
    const u16* browh[2];
    const u16* browl[2];
    #pragma unroll
    for (int j = 0; j < 2; j++) {
        size_t rb = (size_t)(c0 + wc * 32 + j * 16 + n16) * E_DIM;
        browh[j] = wth + rb + qd * 8;
        browl[j] = wtl + rb + qd * 8;
    }

    f32x4 acc[4][2];
    #pragma unroll
    for (int i = 0; i < 4; i++)
        #pragma unroll
        for (int j = 0; j < 2; j++) acc[i][j] = (f32x4){0.f, 0.f, 0.f, 0.f};

    for (int k0 = 0; k0 < E_DIM; k0 += 32) {
        __syncthreads();
        // stage A (x) hi/lo: 512 chunks each
        #pragma unroll
        for (int rep = 0; rep < 2; rep++) {
            int c = rep * 256 + tid;          // chunk = mt*64 + lane'
            int mt = c >> 6;
            int cl = c & 63;
            int cn = cl & 15, cq = cl >> 4;
            size_t aoff = (size_t)(r0 + mt * 16 + cn) * E_DIM + k0 + cq * 8;
            gl_lds16(&xh[aoff], &Ah[c * 8]);
            if (lo) gl_lds16(&xl[aoff], &Al[c * 8]);
        }
        // B frags direct from global (L1/L2 pipe)
        bf16x8 bh[2], bl[2];
        #pragma unroll
        for (int j = 0; j < 2; j++) {
            bh[j] = *(const bf16x8*)&browh[j][k0];
            if (lo) bl[j] = *(const bf16x8*)&browl[j][k0];
        }
        __syncthreads();

        bf16x8 ah[4], al_[4];
        #pragma unroll
        for (int i = 0; i < 4; i++) {
            ah[i] = *(bf16x8*)&Ah[((wr * 4 + i) * 64 + lane) * 8];
            if (lo) al_[i] = *(bf16x8*)&Al[((wr * 4 + i) * 64 + lane) * 8];
        }
        #pragma unroll
        for (int j = 0; j < 2; j++) {
            if (lo) {
                #pragma unroll
                for (int i = 0; i < 4; i++) {
                    acc[i][j] = MFMA16(ah[i], bh[j], acc[i][j]);
                    acc[i][j] = MFMA16(al_[i], bh[j], acc[i][j]);
                    acc[i][j] = MFMA16(ah[i], bl[j], acc[i][j]);
                }
            } else {
                #pragma unroll
                for (int i = 0; i < 4; i++)
                    acc[i][j] = MFMA16(ah[i], bh[j], acc[i][j]);
            }
        }
    }

    if (m == 2) {
        // v epilogue: transpose 128(t) x 64(d) tile through LDS, then
        // coalesced 16B stores along t into vt[h][b][d][t].
        __syncthreads();
        const int VS = 136;                     // u16 stride per d-row
        #pragma unroll
        for (int i = 0; i < 4; i++) {
            int tl = wr * 64 + i * 16 + qd * 4;
            #pragma unroll
            for (int j = 0; j < 2; j++) {
                int d = wc * 32 + j * 16 + n16;
                u16x4 pv;
                #pragma unroll
                for (int r = 0; r < 4; r++) pv[r] = f2bf(acc[i][j][r]);
                *(u16x4*)&SM[d * VS + tl] = pv;
            }
        }
        __syncthreads();
        const int b = r0 >> 11, t0g = r0 & 2047;
        const size_t vbase = (size_t)(h * 2 + b) * HD * T_LEN;
        #pragma unroll
        for (int rep = 0; rep < 4; rep++) {
            int c = rep * 256 + tid;
            int d = c >> 4, toff = (c & 15) * 8;
            u16x8 v8 = *(u16x8*)&SM[d * VS + toff];
            *(u16x8*)&vt[vbase + (size_t)d * T_LEN + t0g + toff] = v8;
        }
    } else {
        const float sc = (m == 0) ? 0.02209708691f : 1.0f;   // q pre-scaled
        u16* oh = (m == 0) ? qh : kh;
        u16* ol = (m == 0) ? ql : kl;
        #pragma unroll
        for (int i = 0; i < 4; i++) {
            int rowb = r0 + wr * 64 + i * 16 + qd * 4;
            #pragma unroll
            for (int j = 0; j < 2; j++) {
                int d = wc * 32 + j * 16 + n16;
                #pragma unroll
                for (int r = 0; r < 4; r++) {
                    int row = rowb + r;
                    int b = row >> 11, t = row & 2047;
                    float f = acc[i][j][r] * sc;
                    u16 hi = f2bf(f);
                    size_t o = ((size_t)((h * 2 + b) * T_LEN + t)) * HD + d;
                    oh[o] = hi;
                    ol[o] = f2bf(f - bf2f(hi));
                }
            }
        }
    }
}

// ---------------------------------------------------------------------------
// Flash attention, transposed formulation. K staged hi/lo in LDS; V frags
// loaded DIRECTLY global->VGPR (wave-invariant addresses -> L1-friendly).
// LDS 25 KB -> 6 blocks/CU.
// ---------------------------------------------------------------------------
__global__ __launch_bounds__(256) void attn_kernel(
    const u16* __restrict__ qh, const u16* __restrict__ ql,
    const u16* __restrict__ kh, const u16* __restrict__ kl,
    const u16* __restrict__ vt, u16* __restrict__ attb)
{
    const int hb = blockIdx.y;       // 0..31
    const int h = hb >> 1, b = hb & 1;
    const int t0 = blockIdx.x * 64;

    const size_t base_tk = (size_t)(h * 2 + b) * T_LEN * HD;
    const size_t base_v  = (size_t)(h * 2 + b) * HD * T_LEN;

    __shared__ __align__(16) u16 BKh[4096], BKl[4096];   // 16KB
    __shared__ __align__(16) u16 PT[4][16][72];          // 9KB, wave-private

    const int tid  = threadIdx.x;
    const int lane = tid & 63;
    const int w    = tid >> 6;
    const int qd   = lane >> 4;
    const int n16  = lane & 15;

    bf16x8 bqh[2], bql[2];
    #pragma unroll
    for (int ks = 0; ks < 2; ks++) {
        size_t o = base_tk + (size_t)(t0 + w * 16 + n16) * HD + ks * 32 + qd * 8;
        bqh[ks] = *(const bf16x8*)&qh[o];
        bql[ks] = *(const bf16x8*)&ql[o];
    }

    // per-lane V row bases: V^T A-frag row = dt*16 + n16 (d), col = keys
    const u16* vrow[4];
    #pragma unroll
    for (int dt = 0; dt < 4; dt++)
        vrow[dt] = vt + base_v + (size_t)(dt * 16 + n16) * T_LEN + qd * 8;

    f32x4 o4[4];
    #pragma unroll
    for (int dt = 0; dt < 4; dt++) o4[dt] = (f32x4){0.f, 0.f, 0.f, 0.f};
    float mr = -1e30f, lr = 0.f;

    for (int st = 0; st < T_LEN / 64; st++) {
        __syncthreads();   // prev-iter BK reads done

        // stage K hi/lo (LDS pipe)
        #pragma unroll
        for (int rep = 0; rep < 2; rep++) {
            int c = rep * 256 + tid;
            int nt = c >> 7, ks = (c >> 6) & 1;
            int cl = c & 63;
            int cn = cl & 15, cq = cl >> 4;
            size_t ko = base_tk + (size_t)(st * 64 + nt * 16 + cn) * HD + ks * 32 + cq * 8;
            gl_lds16(&kh[ko], &BKh[c * 8]);
            gl_lds16(&kl[ko], &BKl[c * 8]);
        }
        // V frags direct from global (L1/L2 pipe) — overlaps with staging wait
        bf16x8 av[4][2];
        #pragma unroll
        for (int dt = 0; dt < 4; dt++)
            #pragma unroll
            for (int ks = 0; ks < 2; ks++)
                av[dt][ks] = *(const bf16x8*)&vrow[dt][st * 64 + ks * 32];
        __syncthreads();   // K resident

        // S^T = K Q^T, 3-term hi/lo
        f32x4 s[4];
        #pragma unroll
        for (int c = 0; c < 4; c++) s[c] = (f32x4){0.f, 0.f, 0.f, 0.f};
        #pragma unroll
        for (int ks = 0; ks < 2; ks++) {
            #pragma unroll
            for (int c = 0; c < 4; c++) {
                bf16x8 akh = *(bf16x8*)&BKh[((c * 2 + ks) * 64 + lane) * 8];
                bf16x8 akl = *(bf16x8*)&BKl[((c * 2 + ks) * 64 + lane) * 8];
                s[c] = MFMA16(akh, bqh[ks], s[c]);
                s[c] = MFMA16(akh, bql[ks], s[c]);
                s[c] = MFMA16(akl, bqh[ks], s[c]);
            }
        }

        // online softmax (query = column n16 -> per-lane scalar state)
        float tmax = s[0][0];
        #pragma unroll
        for (int c = 0; c < 4; c++)
            #pragma unroll
            for (int r = 0; r < 4; r++) tmax = fmaxf(tmax, s[c][r]);
        tmax = fmaxf(tmax, __shfl_xor(tmax, 16));
        tmax = fmaxf(tmax, __shfl_xor(tmax, 32));
        float nm = fmaxf(mr, tmax);
        float al = __expf(mr - nm);
        mr = nm;

        float psum = 0.f;
        #pragma unroll
        for (int c = 0; c < 4; c++) {
            u16x4 pk;
            #pragma unroll
            for (int r = 0; r < 4; r++) {
                float p = __expf(s[c][r] - nm);
                psum += p;
                pk[r] = f2bf(p);
            }
            *(u16x4*)&PT[w][n16][c * 16 + qd * 4] = pk;
        }
        lr = lr * al + psum;
        #pragma unroll
        for (int dt = 0; dt < 4; dt++)
            #pragma unroll
            for (int r = 0; r < 4; r++) o4[dt][r] *= al;

        // O^T += V^T P^T  (PT wave-private: no barrier)
        #pragma unroll
        for (int ks = 0; ks < 2; ks++) {
            bf16x8 bp = *(bf16x8*)&PT[w][n16][ks * 32 + qd * 8];
            #pragma unroll
            for (int dt = 0; dt < 4; dt++)
                o4[dt] = MFMA16(av[dt][ks], bp, o4[dt]);
        }
    }

    lr += __shfl_xor(lr, 16);
    lr += __shfl_xor(lr, 32);
    float inv = 1.f / lr;
    int row = t0 + w * 16 + n16;
    #pragma unroll
    for (int dt = 0; dt < 4; dt++) {
        u16x4 ov;
        #pragma unroll
        for (int r = 0; r < 4; r++) ov[r] = f2bf(o4[dt][r] * inv);
        *(u16x4*)&attb[(size_t)(b * T_LEN + row) * E_DIM + h * HD + dt * 16 + qd * 4] = ov;
    }
}

// ---------------------------------------------------------------------------
// Output projection: out = attb(bf16) @ Wo^T. Retiled 128(M)x64(N), BK=64,
// grid (16,32)=512 blocks -> 6 blocks/CU by LDS (24KB).
// ---------------------------------------------------------------------------
__global__ __launch_bounds__(256) void outproj_mfma_kernel(
    const u16* __restrict__ attb, const u16* __restrict__ wob,
    float* __restrict__ out)
{
    const int c0 = blockIdx.x * 64;
    const int r0 = blockIdx.y * 128;

    __shared__ __align__(16) u16 As[8192], Bs[4096];   // 16KB + 8KB

    const int tid = threadIdx.x;
    const int w = tid >> 6, lane = tid & 63;
    const int qd = lane >> 4, n16 = lane & 15;
    const int wr = w >> 1, wc = w & 1;

    f32x4 acc[4][2];
    #pragma unroll
    for (int i = 0; i < 4; i++)
        #pragma unroll
        for (int j = 0; j < 2; j++) acc[i][j] = (f32x4){0.f, 0.f, 0.f, 0.f};

    for (int k0 = 0; k0 < E_DIM; k0 += 64) {
        __syncthreads();
        // A: 128 rows x 64 k = 1024 chunks; chunk = (mt*2+ks)*64 + lane'
        #pragma unroll
        for (int rep = 0; rep < 4; rep++) {
            int c = rep * 256 + tid;
            int mt = c >> 7, ks = (c >> 6) & 1;
            int cl = c & 63;
            int cn = cl & 15, cq = cl >> 4;
            gl_lds16(&attb[(size_t)(r0 + mt * 16 + cn) * E_DIM + k0 + ks * 32 + cq * 8],
                     &As[c * 8]);
        }
        // B: 64 rows x 64 k = 512 chunks; chunk = (nt*2+ks)*64 + lane'
        #pragma unroll
        for (int rep = 0; rep < 2; rep++) {
            int c = rep * 256 + tid;
            int nt = c >> 7, ks = (c >> 6) & 1;
            int cl = c & 63;
            int cn = cl & 15, cq = cl >> 4;
            gl_lds16(&wob[(size_t)(c0 + nt * 16 + cn) * E_DIM + k0 + ks * 32 + cq * 8],
                     &Bs[c * 8]);
        }
        __syncthreads();

        #pragma unroll
        for (int ks = 0; ks < 2; ks++) {
            bf16x8 a[4];
            #pragma unroll
            for (int i = 0; i < 4; i++)
                a[i] = *(bf16x8*)&As[(((wr * 4 + i) * 2 + ks) * 64 + lane) * 8];
            #pragma unroll
            for (int j = 0; j < 2; j++) {
                bf16x8 bb = *(bf16x8*)&Bs[(((wc * 2 + j) * 2 + ks) * 64 + lane) * 8];
                #pragma unroll
                for (int i = 0; i < 4; i++)
                    acc[i][j] = MFMA16(a[i], bb, acc[i][j]);
            }
        }
    }

    #pragma unroll
    for (int i = 0; i < 4; i++) {
        #pragma unroll
        for (int r = 0; r < 4; r++) {
            int row = r0 + wr * 64 + i * 16 + qd * 4 + r;
            #pragma unroll
            for (int j = 0; j < 2; j++) {
                int col = c0 + wc * 32 + j * 16 + n16;
                out[(size_t)row * E_DIM + col] = acc[i][j][r];
            }
        }
    }
}

extern "C" void kernel_launch(void* const* d_in, const int* in_sizes, int n_in,
                              void* d_out, int out_size, void* d_ws, size_t ws_size,
                              hipStream_t stream)
{
    const float* x  = (const float*)d_in[0];
    const float* Wq = (const float*)d_in[1];
    const float* Wk = (const float*)d_in[2];
    const float* Wv = (const float*)d_in[3];
    const float* Wo = (const float*)d_in[4];
    float* out = (float*)d_out;

    const size_t NX = (size_t)4096 * 1024;
    const size_t NW = (size_t)3072 * 1024;
    const size_t NO = (size_t)1024 * 1024;
    const size_t NQ = (size_t)H_NUM * B_NUM * T_LEN * HD;

    u16* xh  = (u16*)d_ws;
    u16* xl  = xh + NX;
    u16* wth = xl + NX;
    u16* wtl = wth + NW;
    u16* wob = wtl + NW;
    u16* qh  = wob + NO;
    u16* ql  = qh + NQ;
    u16* kh  = ql + NQ;
    u16* kl  = kh + NQ;
    u16* vt  = kl + NQ;
    u16* attb = xh;   // alias: xh dead after qkv_mfma

    convert_x_kernel<<<4096, 256, 0, stream>>>(x, xh, xl);
    convert_w_kernel<<<768, 256, 0, stream>>>(Wq, Wk, Wv, wth, wtl);
    convert_wo_kernel<<<1024, 256, 0, stream>>>(Wo, wob);

    dim3 g1(48, 32);
    qkv_mfma_kernel<<<g1, 256, 0, stream>>>(xh, xl, wth, wtl, qh, ql, kh, kl, vt);

    dim3 g2(T_LEN / 64, H_NUM * B_NUM);
    attn_kernel<<<g2, 256, 0, stream>>>(qh, ql, kh, kl, vt, attb);

    dim3 g3(E_DIM / 64, 4096 / 128);
    outproj_mfma_kernel<<<g3, 256, 0, stream>>>(attb, wob, out);
}

// Round 7
// 330.300 us; speedup vs baseline: 1.4339x; 1.4339x over previous
//
#include <hip/hip_runtime.h>
#include <math.h>

#define E_DIM 1024
#define H_NUM 16
#define HD 64
#define B_NUM 2
#define T_LEN 2048

typedef unsigned short u16;
typedef short bf16x8 __attribute__((ext_vector_type(8)));
typedef float f32x4 __attribute__((ext_vector_type(4)));
typedef unsigned short u16x4 __attribute__((ext_vector_type(4)));
typedef unsigned short u16x8 __attribute__((ext_vector_type(8)));

#define MFMA16(a, b, c) __builtin_amdgcn_mfma_f32_16x16x32_bf16(a, b, c, 0, 0, 0)

__device__ __forceinline__ u16 f2bf(float f) {
    unsigned u = __float_as_uint(f);
    u += 0x7FFFu + ((u >> 16) & 1u);   // RNE
    return (u16)(u >> 16);
}
__device__ __forceinline__ float bf2f(u16 b) {
    return __uint_as_float(((unsigned)b) << 16);
}
// async global->LDS 16B copy. LDS dest must be wave-uniform base + lane*16.
__device__ __forceinline__ void gl_lds16(const void* g, void* l) {
    __builtin_amdgcn_global_load_lds(
        (const __attribute__((address_space(1))) unsigned int*)g,
        (__attribute__((address_space(3))) unsigned int*)l, 16, 0, 0);
}

// Packed fragment-major layouts (chunk = 64 lanes x 8 u16 = 1KB, lane-contiguous):
//   A/B-frag chunk for 16x16x32: lane = ((kk>>3 & 3)<<4) | (row & 15), pos = kk & 7.
// wtp  [ct(192)][ke(32)]  : ct = col/16 over 3072 cols, ke = e/32
// wop  [ct(64)][ke(32)]
// qp/kp[hb(32)][nt(128)][ks(2)] : nt = t/16, ks = d/32
// vp   [hb(32)][st(32)][ks(2)][dt(4)] : key = st*64+ks*32+..., d-row = dt*16+...

// ---------------------------------------------------------------------------
// convert x (fp32 [4096][1024]) -> xh, xl bf16 hi/lo, same row-major layout
// ---------------------------------------------------------------------------
__global__ __launch_bounds__(256) void convert_x_kernel(
    const float* __restrict__ x, u16* __restrict__ xh, u16* __restrict__ xl)
{
    int i = (blockIdx.x * 256 + threadIdx.x) * 4;
    float4 f = *(const float4*)&x[i];
    float fv[4] = {f.x, f.y, f.z, f.w};
    u16x4 h, l;
    #pragma unroll
    for (int j = 0; j < 4; j++) {
        u16 hi = f2bf(fv[j]);
        h[j] = hi;
        l[j] = f2bf(fv[j] - bf2f(hi));
    }
    *(u16x4*)&xh[i] = h;
    *(u16x4*)&xl[i] = l;
}

// ---------------------------------------------------------------------------
// convert Wq/Wk/Wv ([16][1024][64]) -> packed-frag wtp_h/wtp_l.
// grid 768 = m(3) x h(16) x etile(16); block covers 64 cols x 64 e.
// ---------------------------------------------------------------------------
__global__ __launch_bounds__(256) void convert_w_kernel(
    const float* __restrict__ Wq, const float* __restrict__ Wk, const float* __restrict__ Wv,
    u16* __restrict__ wtp_h, u16* __restrict__ wtp_l)
{
    const int bx = blockIdx.x;
    const int m = bx >> 8, h = (bx >> 4) & 15, e0 = (bx & 15) * 64;
    const float* W = (m == 0 ? Wq : (m == 1 ? Wk : Wv));

    __shared__ u16 Th[64][65];   // Th[col][e_local]
    __shared__ u16 Tl[64][65];
    const int tid = threadIdx.x;

    #pragma unroll
    for (int j = 0; j < 16; j++) {
        int idx = j * 256 + tid;
        int e = idx >> 6, i = idx & 63;
        float f = W[((size_t)h * E_DIM + e0 + e) * HD + i];
        u16 hi = f2bf(f);
        Th[i][e] = hi;
        Tl[i][e] = f2bf(f - bf2f(hi));
    }
    __syncthreads();
    // emit 512 chunks: ct_loc(4) x ke_loc(2) x lane(64)
    #pragma unroll
    for (int rep = 0; rep < 2; rep++) {
        int c = rep * 256 + tid;
        int ct_loc = c >> 7, ke_loc = (c >> 6) & 1, lane = c & 63;
        int col = ct_loc * 16 + (lane & 15);
        int el  = ke_loc * 32 + (lane >> 4) * 8;
        int ct_g = m * 64 + h * 4 + ct_loc;
        int ke_g = (bx & 15) * 2 + ke_loc;
        size_t off = ((size_t)ct_g * 32 + ke_g) * 512 + (size_t)lane * 8;
        *(u16x8*)&wtp_h[off] = *(u16x8*)&Th[col][el];
        *(u16x8*)&wtp_l[off] = *(u16x8*)&Tl[col][el];
    }
}

// ---------------------------------------------------------------------------
// convert Wo (fp32 [1024][1024], [out][in]) -> packed-frag wop (bf16).
// grid 512; each thread emits one 8-u16 chunk slice.
// ---------------------------------------------------------------------------
__global__ __launch_bounds__(256) void convert_wo_kernel(
    const float* __restrict__ Wo, u16* __restrict__ wop)
{
    int c = blockIdx.x * 256 + threadIdx.x;   // 0..131071
    int lane = c & 63, ke = (c >> 6) & 31, ct = c >> 11;
    int row = ct * 16 + (lane & 15);
    int e   = ke * 32 + (lane >> 4) * 8;
    const float* src = &Wo[(size_t)row * E_DIM + e];
    float4 f0 = *(const float4*)&src[0];
    float4 f1 = *(const float4*)&src[4];
    float fv[8] = {f0.x, f0.y, f0.z, f0.w, f1.x, f1.y, f1.z, f1.w};
    u16x8 hv;
    #pragma unroll
    for (int j = 0; j < 8; j++) hv[j] = f2bf(fv[j]);
    *(u16x8*)&wop[(size_t)c * 8] = hv;
}

// ---------------------------------------------------------------------------
// Fused QKV GEMM: 128(M) x 64(N) tiles, BK=32, grid (48,32)=1536 blocks.
// A (x) staged hi/lo in LDS (DMA); B (weights) direct from packed wtp
// (lane-contiguous 1KB loads, L2-hot). Epilogues emit packed qp/kp (hi/lo)
// and packed vp.
// ---------------------------------------------------------------------------
__global__ __launch_bounds__(256) void qkv_mfma_kernel(
    const u16* __restrict__ xh, const u16* __restrict__ xl,
    const u16* __restrict__ wtp_h, const u16* __restrict__ wtp_l,
    u16* __restrict__ qp_h, u16* __restrict__ qp_l,
    u16* __restrict__ kp_h, u16* __restrict__ kp_l,
    u16* __restrict__ vp)
{
    const int bx = blockIdx.x;
    const int r0 = blockIdx.y * 128;   // global row (b*T + t)
    const int m  = bx >> 4;            // 0=q 1=k 2=v
    const int h  = bx & 15;            // head
    const bool lo = (m != 2);

    __shared__ __align__(16) u16 SM[8704];   // A hi/lo 8192 + v-transpose slack
    u16* Ah = SM;
    u16* Al = SM + 4096;

    const int tid = threadIdx.x;
    const int w = tid >> 6, lane = tid & 63;
    const int qd = lane >> 4, n16 = lane & 15;
    const int wr = w >> 1, wc = w & 1;   // rows wr*64..+63, cols wc*32..+31

    f32x4 acc[4][2];
    #pragma unroll
    for (int i = 0; i < 4; i++)
        #pragma unroll
        for (int j = 0; j < 2; j++) acc[i][j] = (f32x4){0.f, 0.f, 0.f, 0.f};

    for (int k0 = 0; k0 < E_DIM; k0 += 32) {
        __syncthreads();
        // stage A (x) hi/lo: 512 chunks each
        #pragma unroll
        for (int rep = 0; rep < 2; rep++) {
            int c = rep * 256 + tid;          // chunk = mt*64 + lane'
            int mt = c >> 6;
            int cl = c & 63;
            int cn = cl & 15, cq = cl >> 4;
            size_t aoff = (size_t)(r0 + mt * 16 + cn) * E_DIM + k0 + cq * 8;
            gl_lds16(&xh[aoff], &Ah[c * 8]);
            if (lo) gl_lds16(&xl[aoff], &Al[c * 8]);
        }
        // B frags direct from packed global (coalesced 1KB per load)
        bf16x8 bh[2], bl[2];
        const int ke = k0 >> 5;
        #pragma unroll
        for (int j = 0; j < 2; j++) {
            int ct = bx * 4 + wc * 2 + j;
            size_t off = ((size_t)ct * 32 + ke) * 512 + (size_t)lane * 8;
            bh[j] = *(const bf16x8*)&wtp_h[off];
            if (lo) bl[j] = *(const bf16x8*)&wtp_l[off];
        }
        __syncthreads();

        bf16x8 ah[4], al_[4];
        #pragma unroll
        for (int i = 0; i < 4; i++) {
            ah[i] = *(bf16x8*)&Ah[((wr * 4 + i) * 64 + lane) * 8];
            if (lo) al_[i] = *(bf16x8*)&Al[((wr * 4 + i) * 64 + lane) * 8];
        }
        #pragma unroll
        for (int j = 0; j < 2; j++) {
            if (lo) {
                #pragma unroll
                for (int i = 0; i < 4; i++) {
                    acc[i][j] = MFMA16(ah[i], bh[j], acc[i][j]);
                    acc[i][j] = MFMA16(al_[i], bh[j], acc[i][j]);
                    acc[i][j] = MFMA16(ah[i], bl[j], acc[i][j]);
                }
            } else {
                #pragma unroll
                for (int i = 0; i < 4; i++)
                    acc[i][j] = MFMA16(ah[i], bh[j], acc[i][j]);
            }
        }
    }

    const int b  = r0 >> 11;
    const int hb = h * 2 + b;
    const int tloc0 = r0 & 2047;

    if (m == 2) {
        // v epilogue: transpose 128(t) x 64(d) through LDS, emit packed vp.
        __syncthreads();
        const int VS = 136;
        #pragma unroll
        for (int i = 0; i < 4; i++) {
            int tl = wr * 64 + i * 16 + qd * 4;
            #pragma unroll
            for (int j = 0; j < 2; j++) {
                int d = wc * 32 + j * 16 + n16;
                u16x4 pv;
                #pragma unroll
                for (int r = 0; r < 4; r++) pv[r] = f2bf(acc[i][j][r]);
                *(u16x4*)&SM[d * VS + tl] = pv;
            }
        }
        __syncthreads();
        // 1024 chunks: st_loc(2) x ks(2) x dt(4) x lane(64)
        #pragma unroll
        for (int rep = 0; rep < 4; rep++) {
            int c = rep * 256 + tid;
            int st_loc = c >> 9, ks = (c >> 8) & 1, dt = (c >> 6) & 3, cl = c & 63;
            int d  = dt * 16 + (cl & 15);
            int tl = st_loc * 64 + ks * 32 + (cl >> 4) * 8;
            u16x8 v8 = *(u16x8*)&SM[d * VS + tl];
            int st_g = (tloc0 >> 6) + st_loc;
            size_t off = ((((size_t)hb * 32 + st_g) * 2 + ks) * 4 + dt) * 512 + (size_t)cl * 8;
            *(u16x8*)&vp[off] = v8;
        }
    } else {
        // q/k epilogue: hi/lo split into packed qp/kp
        const float sc = (m == 0) ? 0.02209708691f : 1.0f;   // q pre-scaled 1/sqrt(T)
        u16* oh = (m == 0) ? qp_h : kp_h;
        u16* ol = (m == 0) ? qp_l : kp_l;
        #pragma unroll
        for (int i = 0; i < 4; i++) {
            int nt = (tloc0 >> 4) + wr * 4 + i;
            #pragma unroll
            for (int j = 0; j < 2; j++) {
                int lp = ((j * 2 + (n16 >> 3)) << 4);   // | (t&15) added per r
                int pos = n16 & 7;
                size_t cb = (((size_t)hb * 128 + nt) * 2 + wc) * 512;
                #pragma unroll
                for (int r = 0; r < 4; r++) {
                    float f = acc[i][j][r] * sc;
                    u16 hi = f2bf(f);
                    size_t o = cb + (size_t)(lp | (qd * 4 + r)) * 8 + pos;
                    oh[o] = hi;
                    ol[o] = f2bf(f - bf2f(hi));
                }
            }
        }
    }
}

// ---------------------------------------------------------------------------
// Flash attention (transposed): S^T = K Q^T ; O^T = V^T P^T.
// Q direct packed->VGPR; K DMA-staged from packed (block-linear source);
// V direct packed->VGPR (lane-contiguous). PT wave-private LDS round-trip.
// ---------------------------------------------------------------------------
__global__ __launch_bounds__(256) void attn_kernel(
    const u16* __restrict__ qp_h, const u16* __restrict__ qp_l,
    const u16* __restrict__ kp_h, const u16* __restrict__ kp_l,
    const u16* __restrict__ vp, u16* __restrict__ attb)
{
    const int hb = blockIdx.y;       // 0..31 (= h*2 + b)
    const int h = hb >> 1, b = hb & 1;
    const int t0 = blockIdx.x * 64;

    __shared__ __align__(16) u16 BKh[4096], BKl[4096];   // 16KB
    __shared__ __align__(16) u16 PT[4][16][72];          // 9KB, wave-private

    const int tid  = threadIdx.x;
    const int lane = tid & 63;
    const int w    = tid >> 6;
    const int qd   = lane >> 4;
    const int n16  = lane & 15;

    // Q^T B-frags direct from packed (scale folded in)
    bf16x8 bqh[2], bql[2];
    {
        int qt = (t0 >> 4) + w;
        #pragma unroll
        for (int ks = 0; ks < 2; ks++) {
            size_t off = (((size_t)hb * 128 + qt) * 2 + ks) * 512 + (size_t)lane * 8;
            bqh[ks] = *(const bf16x8*)&qp_h[off];
            bql[ks] = *(const bf16x8*)&qp_l[off];
        }
    }

    f32x4 o4[4];
    #pragma unroll
    for (int dt = 0; dt < 4; dt++) o4[dt] = (f32x4){0.f, 0.f, 0.f, 0.f};
    float mr = -1e30f, lr = 0.f;

    for (int st = 0; st < T_LEN / 64; st++) {
        __syncthreads();   // prev-iter BK reads done

        // stage K hi/lo from packed layout: source is block-linear
        const size_t kb = ((size_t)hb * 128 + st * 4) * 2 * 512;   // u16 offset
        #pragma unroll
        for (int rep = 0; rep < 2; rep++) {
            int c = rep * 256 + tid;
            gl_lds16(&kp_h[kb + (size_t)c * 8], &BKh[c * 8]);
            gl_lds16(&kp_l[kb + (size_t)c * 8], &BKl[c * 8]);
        }
        // V^T A-frags direct from packed (lane-contiguous, L2-hot)
        bf16x8 av[4][2];
        #pragma unroll
        for (int ks = 0; ks < 2; ks++)
            #pragma unroll
            for (int dt = 0; dt < 4; dt++) {
                size_t off = ((((size_t)hb * 32 + st) * 2 + ks) * 4 + dt) * 512 + (size_t)lane * 8;
                av[dt][ks] = *(const bf16x8*)&vp[off];
            }
        __syncthreads();   // K resident

        // S^T = K Q^T, 3-term hi/lo
        f32x4 s[4];
        #pragma unroll
        for (int c = 0; c < 4; c++) s[c] = (f32x4){0.f, 0.f, 0.f, 0.f};
        #pragma unroll
        for (int ks = 0; ks < 2; ks++) {
            #pragma unroll
            for (int c = 0; c < 4; c++) {
                bf16x8 akh = *(bf16x8*)&BKh[((c * 2 + ks) * 64 + lane) * 8];
                bf16x8 akl = *(bf16x8*)&BKl[((c * 2 + ks) * 64 + lane) * 8];
                s[c] = MFMA16(akh, bqh[ks], s[c]);
                s[c] = MFMA16(akh, bql[ks], s[c]);
                s[c] = MFMA16(akl, bqh[ks], s[c]);
            }
        }

        // online softmax: query = column n16 -> per-lane scalar state
        float tmax = s[0][0];
        #pragma unroll
        for (int c = 0; c < 4; c++)
            #pragma unroll
            for (int r = 0; r < 4; r++) tmax = fmaxf(tmax, s[c][r]);
        tmax = fmaxf(tmax, __shfl_xor(tmax, 16));
        tmax = fmaxf(tmax, __shfl_xor(tmax, 32));
        float nm = fmaxf(mr, tmax);
        float al = __expf(mr - nm);
        mr = nm;

        float psum = 0.f;
        #pragma unroll
        for (int c = 0; c < 4; c++) {
            u16x4 pk;
            #pragma unroll
            for (int r = 0; r < 4; r++) {
                float p = __expf(s[c][r] - nm);
                psum += p;
                pk[r] = f2bf(p);
            }
            *(u16x4*)&PT[w][n16][c * 16 + qd * 4] = pk;
        }
        lr = lr * al + psum;
        #pragma unroll
        for (int dt = 0; dt < 4; dt++)
            #pragma unroll
            for (int r = 0; r < 4; r++) o4[dt][r] *= al;

        // O^T += V^T P^T  (PT wave-private: no barrier)
        #pragma unroll
        for (int ks = 0; ks < 2; ks++) {
            bf16x8 bp = *(bf16x8*)&PT[w][n16][ks * 32 + qd * 8];
            #pragma unroll
            for (int dt = 0; dt < 4; dt++)
                o4[dt] = MFMA16(av[dt][ks], bp, o4[dt]);
        }
    }

    lr += __shfl_xor(lr, 16);
    lr += __shfl_xor(lr, 32);
    float inv = 1.f / lr;
    int row = t0 + w * 16 + n16;
    #pragma unroll
    for (int dt = 0; dt < 4; dt++) {
        u16x4 ov;
        #pragma unroll
        for (int r = 0; r < 4; r++) ov[r] = f2bf(o4[dt][r] * inv);
        *(u16x4*)&attb[(size_t)(b * T_LEN + row) * E_DIM + h * HD + dt * 16 + qd * 4] = ov;
    }
}

// ---------------------------------------------------------------------------
// Output projection: out(4096x1024 fp32) = attb(bf16) @ Wo^T.
// 128(M) x 64(N), BK=64, grid (16,32)=512 blocks. A staged; B direct packed.
// ---------------------------------------------------------------------------
__global__ __launch_bounds__(256) void outproj_mfma_kernel(
    const u16* __restrict__ attb, const u16* __restrict__ wop,
    float* __restrict__ out)
{
    const int c0 = blockIdx.x * 64;
    const int r0 = blockIdx.y * 128;

    __shared__ __align__(16) u16 As[8192];   // 16KB

    const int tid = threadIdx.x;
    const int w = tid >> 6, lane = tid & 63;
    const int qd = lane >> 4, n16 = lane & 15;
    const int wr = w >> 1, wc = w & 1;

    f32x4 acc[4][2];
    #pragma unroll
    for (int i = 0; i < 4; i++)
        #pragma unroll
        for (int j = 0; j < 2; j++) acc[i][j] = (f32x4){0.f, 0.f, 0.f, 0.f};

    for (int k0 = 0; k0 < E_DIM; k0 += 64) {
        __syncthreads();
        // A: 128 rows x 64 k = 1024 chunks; chunk = (mt*2+ks)*64 + lane'
        #pragma unroll
        for (int rep = 0; rep < 4; rep++) {
            int c = rep * 256 + tid;
            int mt = c >> 7, ks = (c >> 6) & 1;
            int cl = c & 63;
            int cn = cl & 15, cq = cl >> 4;
            gl_lds16(&attb[(size_t)(r0 + mt * 16 + cn) * E_DIM + k0 + ks * 32 + cq * 8],
                     &As[c * 8]);
        }
        // B direct from packed wop
        bf16x8 bb[2][2];
        #pragma unroll
        for (int j = 0; j < 2; j++) {
            int ct = (c0 >> 4) + wc * 2 + j;
            #pragma unroll
            for (int ks = 0; ks < 2; ks++) {
                int ke = (k0 >> 5) + ks;
                bb[j][ks] = *(const bf16x8*)&wop[((size_t)ct * 32 + ke) * 512 + (size_t)lane * 8];
            }
        }
        __syncthreads();

        #pragma unroll
        for (int ks = 0; ks < 2; ks++) {
            bf16x8 a[4];
            #pragma unroll
            for (int i = 0; i < 4; i++)
                a[i] = *(bf16x8*)&As[(((wr * 4 + i) * 2 + ks) * 64 + lane) * 8];
            #pragma unroll
            for (int j = 0; j < 2; j++)
                #pragma unroll
                for (int i = 0; i < 4; i++)
                    acc[i][j] = MFMA16(a[i], bb[j][ks], acc[i][j]);
        }
    }

    #pragma unroll
    for (int i = 0; i < 4; i++) {
        #pragma unroll
        for (int r = 0; r < 4; r++) {
            int row = r0 + wr * 64 + i * 16 + qd * 4 + r;
            #pragma unroll
            for (int j = 0; j < 2; j++) {
                int col = c0 + wc * 32 + j * 16 + n16;
                out[(size_t)row * E_DIM + col] = acc[i][j][r];
            }
        }
    }
}

extern "C" void kernel_launch(void* const* d_in, const int* in_sizes, int n_in,
                              void* d_out, int out_size, void* d_ws, size_t ws_size,
                              hipStream_t stream)
{
    const float* x  = (const float*)d_in[0];
    const float* Wq = (const float*)d_in[1];
    const float* Wk = (const float*)d_in[2];
    const float* Wv = (const float*)d_in[3];
    const float* Wo = (const float*)d_in[4];
    float* out = (float*)d_out;

    const size_t NX = (size_t)4096 * 1024;
    const size_t NW = (size_t)3072 * 1024;
    const size_t NO = (size_t)1024 * 1024;
    const size_t NQ = (size_t)H_NUM * B_NUM * T_LEN * HD;

    u16* xh   = (u16*)d_ws;
    u16* xl   = xh + NX;
    u16* wtph = xl + NX;
    u16* wtpl = wtph + NW;
    u16* wop  = wtpl + NW;
    u16* qph  = wop + NO;
    u16* qpl  = qph + NQ;
    u16* kph  = qpl + NQ;
    u16* kpl  = kph + NQ;
    u16* vp   = kpl + NQ;
    u16* attb = xh;   // alias: xh dead after qkv_mfma

    convert_x_kernel<<<4096, 256, 0, stream>>>(x, xh, xl);
    convert_w_kernel<<<768, 256, 0, stream>>>(Wq, Wk, Wv, wtph, wtpl);
    convert_wo_kernel<<<512, 256, 0, stream>>>(Wo, wop);

    dim3 g1(48, 32);
    qkv_mfma_kernel<<<g1, 256, 0, stream>>>(xh, xl, wtph, wtpl, qph, qpl, kph, kpl, vp);

    dim3 g2(T_LEN / 64, H_NUM * B_NUM);
    attn_kernel<<<g2, 256, 0, stream>>>(qph, qpl, kph, kpl, vp, attb);

    dim3 g3(E_DIM / 64, 4096 / 128);
    outproj_mfma_kernel<<<g3, 256, 0, stream>>>(attb, wop, out);
}

// Round 8
// 297.670 us; speedup vs baseline: 1.5911x; 1.1096x over previous
//
#include <hip/hip_runtime.h>
#include <math.h>

#define E_DIM 1024
#define H_NUM 16
#define HD 64
#define B_NUM 2
#define T_LEN 2048

typedef unsigned short u16;
typedef short bf16x8 __attribute__((ext_vector_type(8)));
typedef float f32x4 __attribute__((ext_vector_type(4)));
typedef unsigned short u16x4 __attribute__((ext_vector_type(4)));
typedef unsigned short u16x8 __attribute__((ext_vector_type(8)));

#define MFMA16(a, b, c) __builtin_amdgcn_mfma_f32_16x16x32_bf16(a, b, c, 0, 0, 0)

__device__ __forceinline__ u16 f2bf(float f) {
    unsigned u = __float_as_uint(f);
    u += 0x7FFFu + ((u >> 16) & 1u);   // RNE
    return (u16)(u >> 16);
}
__device__ __forceinline__ float bf2f(u16 b) {
    return __uint_as_float(((unsigned)b) << 16);
}
// async global->LDS 16B copy. LDS dest must be wave-uniform base + lane*16.
__device__ __forceinline__ void gl_lds16(const void* g, void* l) {
    __builtin_amdgcn_global_load_lds(
        (const __attribute__((address_space(1))) unsigned int*)g,
        (__attribute__((address_space(3))) unsigned int*)l, 16, 0, 0);
}

// Packed fragment-major layouts (chunk = 64 lanes x 8 u16 = 1KB, lane-contiguous):
//   A/B-frag chunk for 16x16x32: lane = ((kk>>3 & 3)<<4) | (row & 15), pos = kk & 7.
// wtp  [ct(192)][ke(32)]  : ct = col/16 over 3072 cols, ke = e/32
// wop  [ct(64)][ke(32)]
// qp/kp[hb(32)][nt(128)][ks(2)] : nt = t/16, ks = d/32
// vp   [hb(32)][st(32)][ks(2)][dt(4)] : key = st*64+..., d-row = dt*16+...

// ---------------------------------------------------------------------------
// convert x (fp32 [4096][1024]) -> xh, xl bf16 hi/lo, same row-major layout
// ---------------------------------------------------------------------------
__global__ __launch_bounds__(256) void convert_x_kernel(
    const float* __restrict__ x, u16* __restrict__ xh, u16* __restrict__ xl)
{
    int i = (blockIdx.x * 256 + threadIdx.x) * 4;
    float4 f = *(const float4*)&x[i];
    float fv[4] = {f.x, f.y, f.z, f.w};
    u16x4 h, l;
    #pragma unroll
    for (int j = 0; j < 4; j++) {
        u16 hi = f2bf(fv[j]);
        h[j] = hi;
        l[j] = f2bf(fv[j] - bf2f(hi));
    }
    *(u16x4*)&xh[i] = h;
    *(u16x4*)&xl[i] = l;
}

// ---------------------------------------------------------------------------
// convert Wq/Wk/Wv ([16][1024][64]) -> packed-frag wtp_h/wtp_l.
// grid 768 = m(3) x h(16) x etile(16); block covers 64 cols x 64 e.
// ---------------------------------------------------------------------------
__global__ __launch_bounds__(256) void convert_w_kernel(
    const float* __restrict__ Wq, const float* __restrict__ Wk, const float* __restrict__ Wv,
    u16* __restrict__ wtp_h, u16* __restrict__ wtp_l)
{
    const int bx = blockIdx.x;
    const int m = bx >> 8, h = (bx >> 4) & 15, e0 = (bx & 15) * 64;
    const float* W = (m == 0 ? Wq : (m == 1 ? Wk : Wv));

    __shared__ u16 Th[64][65];   // Th[col][e_local]
    __shared__ u16 Tl[64][65];
    const int tid = threadIdx.x;

    #pragma unroll
    for (int j = 0; j < 16; j++) {
        int idx = j * 256 + tid;
        int e = idx >> 6, i = idx & 63;
        float f = W[((size_t)h * E_DIM + e0 + e) * HD + i];
        u16 hi = f2bf(f);
        Th[i][e] = hi;
        Tl[i][e] = f2bf(f - bf2f(hi));
    }
    __syncthreads();
    // emit 512 chunks: ct_loc(4) x ke_loc(2) x lane(64)
    #pragma unroll
    for (int rep = 0; rep < 2; rep++) {
        int c = rep * 256 + tid;
        int ct_loc = c >> 7, ke_loc = (c >> 6) & 1, lane = c & 63;
        int col = ct_loc * 16 + (lane & 15);
        int el  = ke_loc * 32 + (lane >> 4) * 8;
        int ct_g = m * 64 + h * 4 + ct_loc;
        int ke_g = (bx & 15) * 2 + ke_loc;
        size_t off = ((size_t)ct_g * 32 + ke_g) * 512 + (size_t)lane * 8;
        *(u16x8*)&wtp_h[off] = *(u16x8*)&Th[col][el];
        *(u16x8*)&wtp_l[off] = *(u16x8*)&Tl[col][el];
    }
}

// ---------------------------------------------------------------------------
// convert Wo (fp32 [1024][1024], [out][in]) -> packed-frag wop (bf16).
// ---------------------------------------------------------------------------
__global__ __launch_bounds__(256) void convert_wo_kernel(
    const float* __restrict__ Wo, u16* __restrict__ wop)
{
    int c = blockIdx.x * 256 + threadIdx.x;   // 0..131071
    int lane = c & 63, ke = (c >> 6) & 31, ct = c >> 11;
    int row = ct * 16 + (lane & 15);
    int e   = ke * 32 + (lane >> 4) * 8;
    const float* src = &Wo[(size_t)row * E_DIM + e];
    float4 f0 = *(const float4*)&src[0];
    float4 f1 = *(const float4*)&src[4];
    float fv[8] = {f0.x, f0.y, f0.z, f0.w, f1.x, f1.y, f1.z, f1.w};
    u16x8 hv;
    #pragma unroll
    for (int j = 0; j < 8; j++) hv[j] = f2bf(fv[j]);
    *(u16x8*)&wop[(size_t)c * 8] = hv;
}

// ---------------------------------------------------------------------------
// Fused QKV GEMM, m97-shape: 128(M) x 128(N) tiles, BK=32, uniform 3-term
// hi/lo for q, k AND v. grid (24, 32) = 768 blocks = 3/CU; launch_bounds
// pins VGPR so all 3 stay resident. A and B staged hi/lo via DMA from packed
// layouts. 48 MFMA / 16 ds_read_b128 per wave per iter (3:1).
// A 128-col tile spans 2 heads (head = h0 + wc).
// ---------------------------------------------------------------------------
__global__ __launch_bounds__(256, 3) void qkv_mfma_kernel(
    const u16* __restrict__ xh, const u16* __restrict__ xl,
    const u16* __restrict__ wtp_h, const u16* __restrict__ wtp_l,
    u16* __restrict__ qp_h, u16* __restrict__ qp_l,
    u16* __restrict__ kp_h, u16* __restrict__ kp_l,
    u16* __restrict__ vp)
{
    const int bx = blockIdx.x;         // 0..23: col-tile over 3072 packed cols
    const int r0 = blockIdx.y * 128;   // global row (b*T + t)
    const int m  = bx >> 3;            // 0=q 1=k 2=v

    // union: staging A hi/lo + B hi/lo (16384 u16 = 32KB) | v-transpose
    // (2 head-halves x 64 d x 136 stride = 17408 u16 = 34.8KB)
    __shared__ __align__(16) u16 SM[17408];
    u16* Ah = SM;             // 4096
    u16* Al = SM + 4096;      // 4096
    u16* Bh = SM + 8192;      // 4096
    u16* Bl = SM + 12288;     // 4096

    const int tid = threadIdx.x;
    const int w = tid >> 6, lane = tid & 63;
    const int qd = lane >> 4, n16 = lane & 15;
    const int wr = w >> 1, wc = w & 1;   // rows wr*64..+63, cols wc*64..+63

    f32x4 acc[4][4];
    #pragma unroll
    for (int i = 0; i < 4; i++)
        #pragma unroll
        for (int j = 0; j < 4; j++) acc[i][j] = (f32x4){0.f, 0.f, 0.f, 0.f};

    for (int k0 = 0; k0 < E_DIM; k0 += 32) {
        __syncthreads();
        const int ke = k0 >> 5;
        // stage A (x) hi/lo: 512 chunks each (8 mt x 64 lanes)
        #pragma unroll
        for (int rep = 0; rep < 2; rep++) {
            int c = rep * 256 + tid;
            int mt = c >> 6;
            int cl = c & 63;
            int cn = cl & 15, cq = cl >> 4;
            size_t aoff = (size_t)(r0 + mt * 16 + cn) * E_DIM + k0 + cq * 8;
            gl_lds16(&xh[aoff], &Ah[c * 8]);
            gl_lds16(&xl[aoff], &Al[c * 8]);
        }
        // stage B (weights) hi/lo from packed: 512 chunks each, contiguous 1KB
        #pragma unroll
        for (int rep = 0; rep < 2; rep++) {
            int c = rep * 256 + tid;
            int ct_loc = c >> 6;
            int cl = c & 63;
            size_t boff = ((size_t)(bx * 8 + ct_loc) * 32 + ke) * 512 + (size_t)cl * 8;
            gl_lds16(&wtp_h[boff], &Bh[c * 8]);
            gl_lds16(&wtp_l[boff], &Bl[c * 8]);
        }
        __syncthreads();

        bf16x8 ah[4], al_[4];
        #pragma unroll
        for (int i = 0; i < 4; i++) {
            ah[i]  = *(bf16x8*)&Ah[((wr * 4 + i) * 64 + lane) * 8];
            al_[i] = *(bf16x8*)&Al[((wr * 4 + i) * 64 + lane) * 8];
        }
        #pragma unroll
        for (int j = 0; j < 4; j++) {
            bf16x8 bh = *(bf16x8*)&Bh[((wc * 4 + j) * 64 + lane) * 8];
            bf16x8 bl = *(bf16x8*)&Bl[((wc * 4 + j) * 64 + lane) * 8];
            #pragma unroll
            for (int i = 0; i < 4; i++) {
                acc[i][j] = MFMA16(ah[i], bh, acc[i][j]);
                acc[i][j] = MFMA16(al_[i], bh, acc[i][j]);
                acc[i][j] = MFMA16(ah[i], bl, acc[i][j]);
            }
        }
    }

    const int b  = r0 >> 11;
    const int tloc0 = r0 & 2047;

    if (m == 2) {
        // v epilogue: 128 t x 128 d2 (2 heads). Transpose per head-half
        // through LDS (region per wc), then packed vp stores.
        const int h0 = (bx & 7) * 2;
        __syncthreads();   // all waves done with staging SM
        const int VS = 136;
        u16* TR = SM + wc * 8704;       // this wave-column's head-half region
        #pragma unroll
        for (int i = 0; i < 4; i++) {
            int tl = wr * 64 + i * 16 + qd * 4;
            #pragma unroll
            for (int j = 0; j < 4; j++) {
                int d = j * 16 + n16;    // 0..63 within head-half
                u16x4 pv;
                #pragma unroll
                for (int r = 0; r < 4; r++) pv[r] = f2bf(acc[i][j][r]);
                *(u16x4*)&TR[d * VS + tl] = pv;
            }
        }
        __syncthreads();
        const int st_g0 = tloc0 >> 6;
        #pragma unroll
        for (int rep = 0; rep < 8; rep++) {
            int c = rep * 256 + tid;          // 2048 chunks: hh(2) x 1024
            int hh = c >> 10;
            int idx = c & 1023;               // st_loc(2) ks(2) dt(4) lane(64)
            int st_loc = idx >> 9, ks = (idx >> 8) & 1, dt = (idx >> 6) & 3, cl = idx & 63;
            int d  = dt * 16 + (cl & 15);
            int tl = st_loc * 64 + ks * 32 + (cl >> 4) * 8;
            u16x8 v8 = *(u16x8*)&SM[hh * 8704 + d * VS + tl];
            int hbv = (h0 + hh) * 2 + b;
            size_t off = ((((size_t)hbv * 32 + st_g0 + st_loc) * 2 + ks) * 4 + dt) * 512
                       + (size_t)cl * 8;
            *(u16x8*)&vp[off] = v8;
        }
    } else {
        // q/k epilogue: head = h0 + wc; d = j*16 + n16; hi/lo packed writes.
        const int h0 = (bx & 7) * 2;
        const float sc = (m == 0) ? 0.02209708691f : 1.0f;   // q pre-scaled 1/sqrt(T)
        u16* oh = (m == 0) ? qp_h : kp_h;
        u16* ol = (m == 0) ? qp_l : kp_l;
        const int hb = (h0 + wc) * 2 + b;
        #pragma unroll
        for (int i = 0; i < 4; i++) {
            int nt = (tloc0 >> 4) + wr * 4 + i;
            #pragma unroll
            for (int j = 0; j < 4; j++) {
                int ks = j >> 1;
                int lp = (((j & 1) * 2 + (n16 >> 3)) << 4);   // | (t&15) per r
                int pos = n16 & 7;
                size_t cb = (((size_t)hb * 128 + nt) * 2 + ks) * 512;
                #pragma unroll
                for (int r = 0; r < 4; r++) {
                    float f = acc[i][j][r] * sc;
                    u16 hi = f2bf(f);
                    size_t o = cb + (size_t)(lp | (qd * 4 + r)) * 8 + pos;
                    oh[o] = hi;
                    ol[o] = f2bf(f - bf2f(hi));
                }
            }
        }
    }
}

// ---------------------------------------------------------------------------
// Flash attention (transposed): S^T = K Q^T ; O^T = V^T P^T.
// Q direct packed->VGPR; K DMA-staged from packed; V direct packed->VGPR.
// PT wave-private LDS round-trip. (unchanged from R7)
// ---------------------------------------------------------------------------
__global__ __launch_bounds__(256) void attn_kernel(
    const u16* __restrict__ qp_h, const u16* __restrict__ qp_l,
    const u16* __restrict__ kp_h, const u16* __restrict__ kp_l,
    const u16* __restrict__ vp, u16* __restrict__ attb)
{
    const int hb = blockIdx.y;       // 0..31 (= h*2 + b)
    const int h = hb >> 1, b = hb & 1;
    const int t0 = blockIdx.x * 64;

    __shared__ __align__(16) u16 BKh[4096], BKl[4096];   // 16KB
    __shared__ __align__(16) u16 PT[4][16][72];          // 9KB, wave-private

    const int tid  = threadIdx.x;
    const int lane = tid & 63;
    const int w    = tid >> 6;
    const int qd   = lane >> 4;
    const int n16  = lane & 15;

    bf16x8 bqh[2], bql[2];
    {
        int qt = (t0 >> 4) + w;
        #pragma unroll
        for (int ks = 0; ks < 2; ks++) {
            size_t off = (((size_t)hb * 128 + qt) * 2 + ks) * 512 + (size_t)lane * 8;
            bqh[ks] = *(const bf16x8*)&qp_h[off];
            bql[ks] = *(const bf16x8*)&qp_l[off];
        }
    }

    f32x4 o4[4];
    #pragma unroll
    for (int dt = 0; dt < 4; dt++) o4[dt] = (f32x4){0.f, 0.f, 0.f, 0.f};
    float mr = -1e30f, lr = 0.f;

    for (int st = 0; st < T_LEN / 64; st++) {
        __syncthreads();   // prev-iter BK reads done

        const size_t kb = ((size_t)hb * 128 + st * 4) * 2 * 512;
        #pragma unroll
        for (int rep = 0; rep < 2; rep++) {
            int c = rep * 256 + tid;
            gl_lds16(&kp_h[kb + (size_t)c * 8], &BKh[c * 8]);
            gl_lds16(&kp_l[kb + (size_t)c * 8], &BKl[c * 8]);
        }
        bf16x8 av[4][2];
        #pragma unroll
        for (int ks = 0; ks < 2; ks++)
            #pragma unroll
            for (int dt = 0; dt < 4; dt++) {
                size_t off = ((((size_t)hb * 32 + st) * 2 + ks) * 4 + dt) * 512 + (size_t)lane * 8;
                av[dt][ks] = *(const bf16x8*)&vp[off];
            }
        __syncthreads();   // K resident

        f32x4 s[4];
        #pragma unroll
        for (int c = 0; c < 4; c++) s[c] = (f32x4){0.f, 0.f, 0.f, 0.f};
        #pragma unroll
        for (int ks = 0; ks < 2; ks++) {
            #pragma unroll
            for (int c = 0; c < 4; c++) {
                bf16x8 akh = *(bf16x8*)&BKh[((c * 2 + ks) * 64 + lane) * 8];
                bf16x8 akl = *(bf16x8*)&BKl[((c * 2 + ks) * 64 + lane) * 8];
                s[c] = MFMA16(akh, bqh[ks], s[c]);
                s[c] = MFMA16(akh, bql[ks], s[c]);
                s[c] = MFMA16(akl, bqh[ks], s[c]);
            }
        }

        float tmax = s[0][0];
        #pragma unroll
        for (int c = 0; c < 4; c++)
            #pragma unroll
            for (int r = 0; r < 4; r++) tmax = fmaxf(tmax, s[c][r]);
        tmax = fmaxf(tmax, __shfl_xor(tmax, 16));
        tmax = fmaxf(tmax, __shfl_xor(tmax, 32));
        float nm = fmaxf(mr, tmax);
        float al = __expf(mr - nm);
        mr = nm;

        float psum = 0.f;
        #pragma unroll
        for (int c = 0; c < 4; c++) {
            u16x4 pk;
            #pragma unroll
            for (int r = 0; r < 4; r++) {
                float p = __expf(s[c][r] - nm);
                psum += p;
                pk[r] = f2bf(p);
            }
            *(u16x4*)&PT[w][n16][c * 16 + qd * 4] = pk;
        }
        lr = lr * al + psum;
        #pragma unroll
        for (int dt = 0; dt < 4; dt++)
            #pragma unroll
            for (int r = 0; r < 4; r++) o4[dt][r] *= al;

        #pragma unroll
        for (int ks = 0; ks < 2; ks++) {
            bf16x8 bp = *(bf16x8*)&PT[w][n16][ks * 32 + qd * 8];
            #pragma unroll
            for (int dt = 0; dt < 4; dt++)
                o4[dt] = MFMA16(av[dt][ks], bp, o4[dt]);
        }
    }

    lr += __shfl_xor(lr, 16);
    lr += __shfl_xor(lr, 32);
    float inv = 1.f / lr;
    int row = t0 + w * 16 + n16;
    #pragma unroll
    for (int dt = 0; dt < 4; dt++) {
        u16x4 ov;
        #pragma unroll
        for (int r = 0; r < 4; r++) ov[r] = f2bf(o4[dt][r] * inv);
        *(u16x4*)&attb[(size_t)(b * T_LEN + row) * E_DIM + h * HD + dt * 16 + qd * 4] = ov;
    }
}

// ---------------------------------------------------------------------------
// Output projection: out(4096x1024 fp32) = attb(bf16) @ Wo^T.
// 128(M) x 64(N), BK=64, grid (16,32)=512 blocks. A staged; B direct packed.
// ---------------------------------------------------------------------------
__global__ __launch_bounds__(256) void outproj_mfma_kernel(
    const u16* __restrict__ attb, const u16* __restrict__ wop,
    float* __restrict__ out)
{
    const int c0 = blockIdx.x * 64;
    const int r0 = blockIdx.y * 128;

    __shared__ __align__(16) u16 As[8192];   // 16KB

    const int tid = threadIdx.x;
    const int w = tid >> 6, lane = tid & 63;
    const int qd = lane >> 4, n16 = lane & 15;
    const int wr = w >> 1, wc = w & 1;

    f32x4 acc[4][2];
    #pragma unroll
    for (int i = 0; i < 4; i++)
        #pragma unroll
        for (int j = 0; j < 2; j++) acc[i][j] = (f32x4){0.f, 0.f, 0.f, 0.f};

    for (int k0 = 0; k0 < E_DIM; k0 += 64) {
        __syncthreads();
        #pragma unroll
        for (int rep = 0; rep < 4; rep++) {
            int c = rep * 256 + tid;
            int mt = c >> 7, ks = (c >> 6) & 1;
            int cl = c & 63;
            int cn = cl & 15, cq = cl >> 4;
            gl_lds16(&attb[(size_t)(r0 + mt * 16 + cn) * E_DIM + k0 + ks * 32 + cq * 8],
                     &As[c * 8]);
        }
        bf16x8 bb[2][2];
        #pragma unroll
        for (int j = 0; j < 2; j++) {
            int ct = (c0 >> 4) + wc * 2 + j;
            #pragma unroll
            for (int ks = 0; ks < 2; ks++) {
                int ke = (k0 >> 5) + ks;
                bb[j][ks] = *(const bf16x8*)&wop[((size_t)ct * 32 + ke) * 512 + (size_t)lane * 8];
            }
        }
        __syncthreads();

        #pragma unroll
        for (int ks = 0; ks < 2; ks++) {
            bf16x8 a[4];
            #pragma unroll
            for (int i = 0; i < 4; i++)
                a[i] = *(bf16x8*)&As[(((wr * 4 + i) * 2 + ks) * 64 + lane) * 8];
            #pragma unroll
            for (int j = 0; j < 2; j++)
                #pragma unroll
                for (int i = 0; i < 4; i++)
                    acc[i][j] = MFMA16(a[i], bb[j][ks], acc[i][j]);
        }
    }

    #pragma unroll
    for (int i = 0; i < 4; i++) {
        #pragma unroll
        for (int r = 0; r < 4; r++) {
            int row = r0 + wr * 64 + i * 16 + qd * 4 + r;
            #pragma unroll
            for (int j = 0; j < 2; j++) {
                int col = c0 + wc * 32 + j * 16 + n16;
                out[(size_t)row * E_DIM + col] = acc[i][j][r];
            }
        }
    }
}

extern "C" void kernel_launch(void* const* d_in, const int* in_sizes, int n_in,
                              void* d_out, int out_size, void* d_ws, size_t ws_size,
                              hipStream_t stream)
{
    const float* x  = (const float*)d_in[0];
    const float* Wq = (const float*)d_in[1];
    const float* Wk = (const float*)d_in[2];
    const float* Wv = (const float*)d_in[3];
    const float* Wo = (const float*)d_in[4];
    float* out = (float*)d_out;

    const size_t NX = (size_t)4096 * 1024;
    const size_t NW = (size_t)3072 * 1024;
    const size_t NO = (size_t)1024 * 1024;
    const size_t NQ = (size_t)H_NUM * B_NUM * T_LEN * HD;

    u16* xh   = (u16*)d_ws;
    u16* xl   = xh + NX;
    u16* wtph = xl + NX;
    u16* wtpl = wtph + NW;
    u16* wop  = wtpl + NW;
    u16* qph  = wop + NO;
    u16* qpl  = qph + NQ;
    u16* kph  = qpl + NQ;
    u16* kpl  = kph + NQ;
    u16* vp   = kpl + NQ;
    u16* attb = xh;   // alias: xh dead after qkv_mfma

    convert_x_kernel<<<4096, 256, 0, stream>>>(x, xh, xl);
    convert_w_kernel<<<768, 256, 0, stream>>>(Wq, Wk, Wv, wtph, wtpl);
    convert_wo_kernel<<<512, 256, 0, stream>>>(Wo, wop);

    dim3 g1(24, 32);
    qkv_mfma_kernel<<<g1, 256, 0, stream>>>(xh, xl, wtph, wtpl, qph, qpl, kph, kpl, vp);

    dim3 g2(T_LEN / 64, H_NUM * B_NUM);
    attn_kernel<<<g2, 256, 0, stream>>>(qph, qpl, kph, kpl, vp, attb);

    dim3 g3(E_DIM / 64, 4096 / 128);
    outproj_mfma_kernel<<<g3, 256, 0, stream>>>(attb, wop, out);
}

// Round 9
// 278.312 us; speedup vs baseline: 1.7018x; 1.0696x over previous
//
#include <hip/hip_runtime.h>
#include <math.h>

#define E_DIM 1024
#define H_NUM 16
#define HD 64
#define B_NUM 2
#define T_LEN 2048

typedef unsigned short u16;
typedef short bf16x8 __attribute__((ext_vector_type(8)));
typedef float f32x4 __attribute__((ext_vector_type(4)));
typedef unsigned short u16x4 __attribute__((ext_vector_type(4)));
typedef unsigned short u16x8 __attribute__((ext_vector_type(8)));
typedef unsigned int u32x2 __attribute__((ext_vector_type(2)));

#define MFMA16(a, b, c) __builtin_amdgcn_mfma_f32_16x16x32_bf16(a, b, c, 0, 0, 0)

__device__ __forceinline__ u16 f2bf(float f) {
    unsigned u = __float_as_uint(f);
    u += 0x7FFFu + ((u >> 16) & 1u);   // RNE
    return (u16)(u >> 16);
}
__device__ __forceinline__ float bf2f(u16 b) {
    return __uint_as_float(((unsigned)b) << 16);
}
// async global->LDS 16B copy. LDS dest must be wave-uniform base + lane*16.
__device__ __forceinline__ void gl_lds16(const void* g, void* l) {
    __builtin_amdgcn_global_load_lds(
        (const __attribute__((address_space(1))) unsigned int*)g,
        (__attribute__((address_space(3))) unsigned int*)l, 16, 0, 0);
}

// Packed fragment-major layouts (chunk = 64 lanes x 8 u16 = 1KB, lane-contiguous):
//   A/B-frag chunk for 16x16x32: lane = ((kk>>3 & 3)<<4) | (row & 15), pos = kk & 7.
// wtp  [ct(192)][ke(32)]  : ct = col/16 over 3072 cols, ke = e/32
// wop  [ct(64)][ke(32)]
// qp/kp[hb(32)][nt(128)][ks(2)] : nt = t/16, ks = d/32
// vp   [hb(32)][st(32)][ks(2)][dt(4)] : key = st*64+..., d-row = dt*16+...

// ---------------------------------------------------------------------------
// convert x (fp32 [4096][1024]) -> xh, xl bf16 hi/lo, same row-major layout
// ---------------------------------------------------------------------------
__global__ __launch_bounds__(256) void convert_x_kernel(
    const float* __restrict__ x, u16* __restrict__ xh, u16* __restrict__ xl)
{
    int i = (blockIdx.x * 256 + threadIdx.x) * 4;
    float4 f = *(const float4*)&x[i];
    float fv[4] = {f.x, f.y, f.z, f.w};
    u16x4 h, l;
    #pragma unroll
    for (int j = 0; j < 4; j++) {
        u16 hi = f2bf(fv[j]);
        h[j] = hi;
        l[j] = f2bf(fv[j] - bf2f(hi));
    }
    *(u16x4*)&xh[i] = h;
    *(u16x4*)&xl[i] = l;
}

// ---------------------------------------------------------------------------
// convert Wq/Wk/Wv ([16][1024][64]) -> packed-frag wtp_h/wtp_l.
// ---------------------------------------------------------------------------
__global__ __launch_bounds__(256) void convert_w_kernel(
    const float* __restrict__ Wq, const float* __restrict__ Wk, const float* __restrict__ Wv,
    u16* __restrict__ wtp_h, u16* __restrict__ wtp_l)
{
    const int bx = blockIdx.x;
    const int m = bx >> 8, h = (bx >> 4) & 15, e0 = (bx & 15) * 64;
    const float* W = (m == 0 ? Wq : (m == 1 ? Wk : Wv));

    __shared__ u16 Th[64][65];   // Th[col][e_local]
    __shared__ u16 Tl[64][65];
    const int tid = threadIdx.x;

    #pragma unroll
    for (int j = 0; j < 16; j++) {
        int idx = j * 256 + tid;
        int e = idx >> 6, i = idx & 63;
        float f = W[((size_t)h * E_DIM + e0 + e) * HD + i];
        u16 hi = f2bf(f);
        Th[i][e] = hi;
        Tl[i][e] = f2bf(f - bf2f(hi));
    }
    __syncthreads();
    #pragma unroll
    for (int rep = 0; rep < 2; rep++) {
        int c = rep * 256 + tid;
        int ct_loc = c >> 7, ke_loc = (c >> 6) & 1, lane = c & 63;
        int col = ct_loc * 16 + (lane & 15);
        int el  = ke_loc * 32 + (lane >> 4) * 8;
        int ct_g = m * 64 + h * 4 + ct_loc;
        int ke_g = (bx & 15) * 2 + ke_loc;
        size_t off = ((size_t)ct_g * 32 + ke_g) * 512 + (size_t)lane * 8;
        *(u16x8*)&wtp_h[off] = *(u16x8*)&Th[col][el];
        *(u16x8*)&wtp_l[off] = *(u16x8*)&Tl[col][el];
    }
}

// ---------------------------------------------------------------------------
// convert Wo (fp32 [1024][1024], [out][in]) -> packed-frag wop (bf16).
// ---------------------------------------------------------------------------
__global__ __launch_bounds__(256) void convert_wo_kernel(
    const float* __restrict__ Wo, u16* __restrict__ wop)
{
    int c = blockIdx.x * 256 + threadIdx.x;   // 0..131071
    int lane = c & 63, ke = (c >> 6) & 31, ct = c >> 11;
    int row = ct * 16 + (lane & 15);
    int e   = ke * 32 + (lane >> 4) * 8;
    const float* src = &Wo[(size_t)row * E_DIM + e];
    float4 f0 = *(const float4*)&src[0];
    float4 f1 = *(const float4*)&src[4];
    float fv[8] = {f0.x, f0.y, f0.z, f0.w, f1.x, f1.y, f1.z, f1.w};
    u16x8 hv;
    #pragma unroll
    for (int j = 0; j < 8; j++) hv[j] = f2bf(fv[j]);
    *(u16x8*)&wop[(size_t)c * 8] = hv;
}

// ---------------------------------------------------------------------------
// Fused QKV GEMM, 128x128 tiles, BK=32, uniform 3-term hi/lo.
// grid (24, 32) = 768 blocks = 3/CU. q pre-scaled by log2(e)/sqrt(T) so
// attention softmax runs in exp2 domain.
// ---------------------------------------------------------------------------
__global__ __launch_bounds__(256, 3) void qkv_mfma_kernel(
    const u16* __restrict__ xh, const u16* __restrict__ xl,
    const u16* __restrict__ wtp_h, const u16* __restrict__ wtp_l,
    u16* __restrict__ qp_h, u16* __restrict__ qp_l,
    u16* __restrict__ kp_h, u16* __restrict__ kp_l,
    u16* __restrict__ vp)
{
    const int bx = blockIdx.x;         // 0..23: col-tile over 3072 packed cols
    const int r0 = blockIdx.y * 128;   // global row (b*T + t)
    const int m  = bx >> 3;            // 0=q 1=k 2=v

    __shared__ __align__(16) u16 SM[17408];
    u16* Ah = SM;             // 4096
    u16* Al = SM + 4096;      // 4096
    u16* Bh = SM + 8192;      // 4096
    u16* Bl = SM + 12288;     // 4096

    const int tid = threadIdx.x;
    const int w = tid >> 6, lane = tid & 63;
    const int qd = lane >> 4, n16 = lane & 15;
    const int wr = w >> 1, wc = w & 1;   // rows wr*64..+63, cols wc*64..+63

    f32x4 acc[4][4];
    #pragma unroll
    for (int i = 0; i < 4; i++)
        #pragma unroll
        for (int j = 0; j < 4; j++) acc[i][j] = (f32x4){0.f, 0.f, 0.f, 0.f};

    for (int k0 = 0; k0 < E_DIM; k0 += 32) {
        __syncthreads();
        const int ke = k0 >> 5;
        #pragma unroll
        for (int rep = 0; rep < 2; rep++) {
            int c = rep * 256 + tid;
            int mt = c >> 6;
            int cl = c & 63;
            int cn = cl & 15, cq = cl >> 4;
            size_t aoff = (size_t)(r0 + mt * 16 + cn) * E_DIM + k0 + cq * 8;
            gl_lds16(&xh[aoff], &Ah[c * 8]);
            gl_lds16(&xl[aoff], &Al[c * 8]);
        }
        #pragma unroll
        for (int rep = 0; rep < 2; rep++) {
            int c = rep * 256 + tid;
            int ct_loc = c >> 6;
            int cl = c & 63;
            size_t boff = ((size_t)(bx * 8 + ct_loc) * 32 + ke) * 512 + (size_t)cl * 8;
            gl_lds16(&wtp_h[boff], &Bh[c * 8]);
            gl_lds16(&wtp_l[boff], &Bl[c * 8]);
        }
        __syncthreads();

        bf16x8 ah[4], al_[4];
        #pragma unroll
        for (int i = 0; i < 4; i++) {
            ah[i]  = *(bf16x8*)&Ah[((wr * 4 + i) * 64 + lane) * 8];
            al_[i] = *(bf16x8*)&Al[((wr * 4 + i) * 64 + lane) * 8];
        }
        #pragma unroll
        for (int j = 0; j < 4; j++) {
            bf16x8 bh = *(bf16x8*)&Bh[((wc * 4 + j) * 64 + lane) * 8];
            bf16x8 bl = *(bf16x8*)&Bl[((wc * 4 + j) * 64 + lane) * 8];
            #pragma unroll
            for (int i = 0; i < 4; i++) {
                acc[i][j] = MFMA16(ah[i], bh, acc[i][j]);
                acc[i][j] = MFMA16(al_[i], bh, acc[i][j]);
                acc[i][j] = MFMA16(ah[i], bl, acc[i][j]);
            }
        }
    }

    const int b  = r0 >> 11;
    const int tloc0 = r0 & 2047;

    if (m == 2) {
        const int h0 = (bx & 7) * 2;
        __syncthreads();
        const int VS = 136;
        u16* TR = SM + wc * 8704;
        #pragma unroll
        for (int i = 0; i < 4; i++) {
            int tl = wr * 64 + i * 16 + qd * 4;
            #pragma unroll
            for (int j = 0; j < 4; j++) {
                int d = j * 16 + n16;
                u16x4 pv;
                #pragma unroll
                for (int r = 0; r < 4; r++) pv[r] = f2bf(acc[i][j][r]);
                *(u16x4*)&TR[d * VS + tl] = pv;
            }
        }
        __syncthreads();
        const int st_g0 = tloc0 >> 6;
        #pragma unroll
        for (int rep = 0; rep < 8; rep++) {
            int c = rep * 256 + tid;
            int hh = c >> 10;
            int idx = c & 1023;
            int st_loc = idx >> 9, ks = (idx >> 8) & 1, dt = (idx >> 6) & 3, cl = idx & 63;
            int d  = dt * 16 + (cl & 15);
            int tl = st_loc * 64 + ks * 32 + (cl >> 4) * 8;
            u16x8 v8 = *(u16x8*)&SM[hh * 8704 + d * VS + tl];
            int hbv = (h0 + hh) * 2 + b;
            size_t off = ((((size_t)hbv * 32 + st_g0 + st_loc) * 2 + ks) * 4 + dt) * 512
                       + (size_t)cl * 8;
            *(u16x8*)&vp[off] = v8;
        }
    } else {
        const int h0 = (bx & 7) * 2;
        // q pre-scaled by log2(e)/sqrt(2048): softmax runs in exp2 domain
        const float sc = (m == 0) ? 0.031882937f : 1.0f;
        u16* oh = (m == 0) ? qp_h : kp_h;
        u16* ol = (m == 0) ? qp_l : kp_l;
        const int hb = (h0 + wc) * 2 + b;
        #pragma unroll
        for (int i = 0; i < 4; i++) {
            int nt = (tloc0 >> 4) + wr * 4 + i;
            #pragma unroll
            for (int j = 0; j < 4; j++) {
                int ks = j >> 1;
                int lp = (((j & 1) * 2 + (n16 >> 3)) << 4);
                int pos = n16 & 7;
                size_t cb = (((size_t)hb * 128 + nt) * 2 + ks) * 512;
                #pragma unroll
                for (int r = 0; r < 4; r++) {
                    float f = acc[i][j][r] * sc;
                    u16 hi = f2bf(f);
                    size_t o = cb + (size_t)(lp | (qd * 4 + r)) * 8 + pos;
                    oh[o] = hi;
                    ol[o] = f2bf(f - bf2f(hi));
                }
            }
        }
    }
}

// ---------------------------------------------------------------------------
// Flash attention (transposed): S^T = K Q^T ; O^T = V^T P^T.
// R9: exp2-domain softmax (scale folded into q), truncating P pack,
// conditional O-rescale, K-DMA overlapped with softmax+PV, hb-major grid
// for XCD-L2 locality (blockIdx.x = hb so flat%8 == hb%8).
// ---------------------------------------------------------------------------
__global__ __launch_bounds__(256) void attn_kernel(
    const u16* __restrict__ qp_h, const u16* __restrict__ qp_l,
    const u16* __restrict__ kp_h, const u16* __restrict__ kp_l,
    const u16* __restrict__ vp, u16* __restrict__ attb)
{
    const int hb = blockIdx.x;       // 0..31 (= h*2 + b) — XCD = hb%8
    const int h = hb >> 1, b = hb & 1;
    const int t0 = blockIdx.y * 64;

    __shared__ __align__(16) u16 BKh[4096], BKl[4096];   // 16KB
    __shared__ __align__(16) u16 PT[4][16][72];          // 9KB, wave-private

    const int tid  = threadIdx.x;
    const int lane = tid & 63;
    const int w    = tid >> 6;
    const int qd   = lane >> 4;
    const int n16  = lane & 15;

    bf16x8 bqh[2], bql[2];
    {
        int qt = (t0 >> 4) + w;
        #pragma unroll
        for (int ks = 0; ks < 2; ks++) {
            size_t off = (((size_t)hb * 128 + qt) * 2 + ks) * 512 + (size_t)lane * 8;
            bqh[ks] = *(const bf16x8*)&qp_h[off];
            bql[ks] = *(const bf16x8*)&qp_l[off];
        }
    }

    f32x4 o4[4];
    #pragma unroll
    for (int dt = 0; dt < 4; dt++) o4[dt] = (f32x4){0.f, 0.f, 0.f, 0.f};
    float mr = -1e30f, lr = 0.f;

    // prologue: issue K DMA for st=0
    {
        const size_t kb = (size_t)hb * 128 * 2 * 512;
        #pragma unroll
        for (int rep = 0; rep < 2; rep++) {
            int c = rep * 256 + tid;
            gl_lds16(&kp_h[kb + (size_t)c * 8], &BKh[c * 8]);
            gl_lds16(&kp_l[kb + (size_t)c * 8], &BKl[c * 8]);
        }
    }

    for (int st = 0; st < T_LEN / 64; st++) {
        __syncthreads();   // K(st) DMA drained (implicit vmcnt0) + all waves joined

        // V(st) direct global->VGPR: issued now, consumed after softmax
        bf16x8 av[4][2];
        #pragma unroll
        for (int ks = 0; ks < 2; ks++)
            #pragma unroll
            for (int dt = 0; dt < 4; dt++) {
                size_t off = ((((size_t)hb * 32 + st) * 2 + ks) * 4 + dt) * 512 + (size_t)lane * 8;
                av[dt][ks] = *(const bf16x8*)&vp[off];
            }

        // S^T = K Q^T, 3-term hi/lo (reads BK from LDS)
        f32x4 s[4];
        #pragma unroll
        for (int c = 0; c < 4; c++) s[c] = (f32x4){0.f, 0.f, 0.f, 0.f};
        #pragma unroll
        for (int ks = 0; ks < 2; ks++) {
            #pragma unroll
            for (int c = 0; c < 4; c++) {
                bf16x8 akh = *(bf16x8*)&BKh[((c * 2 + ks) * 64 + lane) * 8];
                bf16x8 akl = *(bf16x8*)&BKl[((c * 2 + ks) * 64 + lane) * 8];
                s[c] = MFMA16(akh, bqh[ks], s[c]);
                s[c] = MFMA16(akh, bql[ks], s[c]);
                s[c] = MFMA16(akl, bqh[ks], s[c]);
            }
        }

        __syncthreads();   // all waves done reading BK -> safe to overwrite

        // issue K(st+1) DMA now; it completes during softmax+PV below
        if (st + 1 < T_LEN / 64) {
            const size_t kb = ((size_t)hb * 128 + (st + 1) * 4) * 2 * 512;
            #pragma unroll
            for (int rep = 0; rep < 2; rep++) {
                int c = rep * 256 + tid;
                gl_lds16(&kp_h[kb + (size_t)c * 8], &BKh[c * 8]);
                gl_lds16(&kp_l[kb + (size_t)c * 8], &BKl[c * 8]);
            }
        }

        // online softmax in exp2 domain (query = lane column n16)
        float tmax = s[0][0];
        #pragma unroll
        for (int c = 0; c < 4; c++)
            #pragma unroll
            for (int r = 0; r < 4; r++) tmax = fmaxf(tmax, s[c][r]);
        tmax = fmaxf(tmax, __shfl_xor(tmax, 16));
        tmax = fmaxf(tmax, __shfl_xor(tmax, 32));
        float nm = fmaxf(mr, tmax);
        float al = __builtin_amdgcn_exp2f(mr - nm);   // == 1.0 iff max unchanged
        mr = nm;

        float psum = 0.f;
        #pragma unroll
        for (int c = 0; c < 4; c++) {
            float p0 = __builtin_amdgcn_exp2f(s[c][0] - nm);
            float p1 = __builtin_amdgcn_exp2f(s[c][1] - nm);
            float p2 = __builtin_amdgcn_exp2f(s[c][2] - nm);
            float p3 = __builtin_amdgcn_exp2f(s[c][3] - nm);
            psum += (p0 + p1) + (p2 + p3);
            // truncating bf16 pack (P in [0,1]: bias <= 0.4%, cancels in ratio)
            u32x2 pk;
            pk[0] = (__float_as_uint(p0) >> 16) | (__float_as_uint(p1) & 0xFFFF0000u);
            pk[1] = (__float_as_uint(p2) >> 16) | (__float_as_uint(p3) & 0xFFFF0000u);
            *(u32x2*)&PT[w][n16][c * 16 + qd * 4] = pk;
        }
        if (__any(al != 1.0f)) {
            lr *= al;
            #pragma unroll
            for (int dt = 0; dt < 4; dt++)
                #pragma unroll
                for (int r = 0; r < 4; r++) o4[dt][r] *= al;
        }
        lr += psum;

        // O^T += V^T P^T  (PT wave-private: no barrier)
        #pragma unroll
        for (int ks = 0; ks < 2; ks++) {
            bf16x8 bp = *(bf16x8*)&PT[w][n16][ks * 32 + qd * 8];
            #pragma unroll
            for (int dt = 0; dt < 4; dt++)
                o4[dt] = MFMA16(av[dt][ks], bp, o4[dt]);
        }
    }

    lr += __shfl_xor(lr, 16);
    lr += __shfl_xor(lr, 32);
    float inv = 1.f / lr;
    int row = t0 + w * 16 + n16;
    #pragma unroll
    for (int dt = 0; dt < 4; dt++) {
        u16x4 ov;
        #pragma unroll
        for (int r = 0; r < 4; r++) ov[r] = f2bf(o4[dt][r] * inv);
        *(u16x4*)&attb[(size_t)(b * T_LEN + row) * E_DIM + h * HD + dt * 16 + qd * 4] = ov;
    }
}

// ---------------------------------------------------------------------------
// Output projection: out(4096x1024 fp32) = attb(bf16) @ Wo^T.
// 128(M) x 64(N), BK=64, grid (16,32)=512 blocks. A staged; B direct packed.
// ---------------------------------------------------------------------------
__global__ __launch_bounds__(256) void outproj_mfma_kernel(
    const u16* __restrict__ attb, const u16* __restrict__ wop,
    float* __restrict__ out)
{
    const int c0 = blockIdx.x * 64;
    const int r0 = blockIdx.y * 128;

    __shared__ __align__(16) u16 As[8192];   // 16KB

    const int tid = threadIdx.x;
    const int w = tid >> 6, lane = tid & 63;
    const int qd = lane >> 4, n16 = lane & 15;
    const int wr = w >> 1, wc = w & 1;

    f32x4 acc[4][2];
    #pragma unroll
    for (int i = 0; i < 4; i++)
        #pragma unroll
        for (int j = 0; j < 2; j++) acc[i][j] = (f32x4){0.f, 0.f, 0.f, 0.f};

    for (int k0 = 0; k0 < E_DIM; k0 += 64) {
        __syncthreads();
        #pragma unroll
        for (int rep = 0; rep < 4; rep++) {
            int c = rep * 256 + tid;
            int mt = c >> 7, ks = (c >> 6) & 1;
            int cl = c & 63;
            int cn = cl & 15, cq = cl >> 4;
            gl_lds16(&attb[(size_t)(r0 + mt * 16 + cn) * E_DIM + k0 + ks * 32 + cq * 8],
                     &As[c * 8]);
        }
        bf16x8 bb[2][2];
        #pragma unroll
        for (int j = 0; j < 2; j++) {
            int ct = (c0 >> 4) + wc * 2 + j;
            #pragma unroll
            for (int ks = 0; ks < 2; ks++) {
                int ke = (k0 >> 5) + ks;
                bb[j][ks] = *(const bf16x8*)&wop[((size_t)ct * 32 + ke) * 512 + (size_t)lane * 8];
            }
        }
        __syncthreads();

        #pragma unroll
        for (int ks = 0; ks < 2; ks++) {
            bf16x8 a[4];
            #pragma unroll
            for (int i = 0; i < 4; i++)
                a[i] = *(bf16x8*)&As[(((wr * 4 + i) * 2 + ks) * 64 + lane) * 8];
            #pragma unroll
            for (int j = 0; j < 2; j++)
                #pragma unroll
                for (int i = 0; i < 4; i++)
                    acc[i][j] = MFMA16(a[i], bb[j][ks], acc[i][j]);
        }
    }

    #pragma unroll
    for (int i = 0; i < 4; i++) {
        #pragma unroll
        for (int r = 0; r < 4; r++) {
            int row = r0 + wr * 64 + i * 16 + qd * 4 + r;
            #pragma unroll
            for (int j = 0; j < 2; j++) {
                int col = c0 + wc * 32 + j * 16 + n16;
                out[(size_t)row * E_DIM + col] = acc[i][j][r];
            }
        }
    }
}

extern "C" void kernel_launch(void* const* d_in, const int* in_sizes, int n_in,
                              void* d_out, int out_size, void* d_ws, size_t ws_size,
                              hipStream_t stream)
{
    const float* x  = (const float*)d_in[0];
    const float* Wq = (const float*)d_in[1];
    const float* Wk = (const float*)d_in[2];
    const float* Wv = (const float*)d_in[3];
    const float* Wo = (const float*)d_in[4];
    float* out = (float*)d_out;

    const size_t NX = (size_t)4096 * 1024;
    const size_t NW = (size_t)3072 * 1024;
    const size_t NO = (size_t)1024 * 1024;
    const size_t NQ = (size_t)H_NUM * B_NUM * T_LEN * HD;

    u16* xh   = (u16*)d_ws;
    u16* xl   = xh + NX;
    u16* wtph = xl + NX;
    u16* wtpl = wtph + NW;
    u16* wop  = wtpl + NW;
    u16* qph  = wop + NO;
    u16* qpl  = qph + NQ;
    u16* kph  = qpl + NQ;
    u16* kpl  = kph + NQ;
    u16* vp   = kpl + NQ;
    u16* attb = xh;   // alias: xh dead after qkv_mfma

    convert_x_kernel<<<4096, 256, 0, stream>>>(x, xh, xl);
    convert_w_kernel<<<768, 256, 0, stream>>>(Wq, Wk, Wv, wtph, wtpl);
    convert_wo_kernel<<<512, 256, 0, stream>>>(Wo, wop);

    dim3 g1(24, 32);
    qkv_mfma_kernel<<<g1, 256, 0, stream>>>(xh, xl, wtph, wtpl, qph, qpl, kph, kpl, vp);

    dim3 g2(H_NUM * B_NUM, T_LEN / 64);   // x = hb for XCD-L2 locality
    attn_kernel<<<g2, 256, 0, stream>>>(qph, qpl, kph, kpl, vp, attb);

    dim3 g3(E_DIM / 64, 4096 / 128);
    outproj_mfma_kernel<<<g3, 256, 0, stream>>>(attb, wop, out);
}

// Round 10
// 259.379 us; speedup vs baseline: 1.8260x; 1.0730x over previous
//
#include <hip/hip_runtime.h>
#include <math.h>

#define E_DIM 1024
#define H_NUM 16
#define HD 64
#define B_NUM 2
#define T_LEN 2048

typedef unsigned short u16;
typedef short bf16x8 __attribute__((ext_vector_type(8)));
typedef float f32x4 __attribute__((ext_vector_type(4)));
typedef unsigned short u16x4 __attribute__((ext_vector_type(4)));
typedef unsigned short u16x8 __attribute__((ext_vector_type(8)));
typedef unsigned int u32x2 __attribute__((ext_vector_type(2)));

#define MFMA16(a, b, c) __builtin_amdgcn_mfma_f32_16x16x32_bf16(a, b, c, 0, 0, 0)

__device__ __forceinline__ u16 f2bf(float f) {
    unsigned u = __float_as_uint(f);
    u += 0x7FFFu + ((u >> 16) & 1u);   // RNE
    return (u16)(u >> 16);
}
__device__ __forceinline__ float bf2f(u16 b) {
    return __uint_as_float(((unsigned)b) << 16);
}
// async global->LDS 16B copy. LDS dest must be wave-uniform base + lane*16.
__device__ __forceinline__ void gl_lds16(const void* g, void* l) {
    __builtin_amdgcn_global_load_lds(
        (const __attribute__((address_space(1))) unsigned int*)g,
        (__attribute__((address_space(3))) unsigned int*)l, 16, 0, 0);
}

// Packed fragment-major layouts (chunk = 64 lanes x 8 u16 = 1KB, lane-contiguous):
//   A/B-frag chunk for 16x16x32: lane = ((kk>>3 & 3)<<4) | (row & 15), pos = kk & 7.
// wtp  [ct(192)][ke(32)]  : ct = col/16 over 3072 cols, ke = e/32
// wop  [ct(64)][ke(32)]
// qp/kp[hb(32)][nt(128)][ks(2)] : nt = t/16, ks = d/32
// vp   [hb(32)][st(32)][ks(2)][dt(4)] : key = st*64+..., d-row = dt*16+...

// ---------------------------------------------------------------------------
// Fused conversion kernel: grid 5376 = 4096 (x) + 768 (Wq/k/v) + 512 (Wo).
// Fusing overlaps the three memory phases and saves two launch gaps.
// ---------------------------------------------------------------------------
__global__ __launch_bounds__(256) void convert_all_kernel(
    const float* __restrict__ x,
    const float* __restrict__ Wq, const float* __restrict__ Wk, const float* __restrict__ Wv,
    const float* __restrict__ Wo,
    u16* __restrict__ xh, u16* __restrict__ xl,
    u16* __restrict__ wtp_h, u16* __restrict__ wtp_l,
    u16* __restrict__ wop)
{
    const int bid = blockIdx.x;
    const int tid = threadIdx.x;

    if (bid < 4096) {
        // ---- x -> xh/xl hi-lo split ----
        int i = (bid * 256 + tid) * 4;
        float4 f = *(const float4*)&x[i];
        float fv[4] = {f.x, f.y, f.z, f.w};
        u16x4 h, l;
        #pragma unroll
        for (int j = 0; j < 4; j++) {
            u16 hi = f2bf(fv[j]);
            h[j] = hi;
            l[j] = f2bf(fv[j] - bf2f(hi));
        }
        *(u16x4*)&xh[i] = h;
        *(u16x4*)&xl[i] = l;
    } else if (bid < 4096 + 768) {
        // ---- Wq/Wk/Wv -> packed-frag wtp_h/wtp_l ----
        const int bx = bid - 4096;
        const int m = bx >> 8, h = (bx >> 4) & 15, e0 = (bx & 15) * 64;
        const float* W = (m == 0 ? Wq : (m == 1 ? Wk : Wv));

        __shared__ u16 Th[64][65];   // Th[col][e_local]
        __shared__ u16 Tl[64][65];

        #pragma unroll
        for (int j = 0; j < 16; j++) {
            int idx = j * 256 + tid;
            int e = idx >> 6, i = idx & 63;
            float f = W[((size_t)h * E_DIM + e0 + e) * HD + i];
            u16 hi = f2bf(f);
            Th[i][e] = hi;
            Tl[i][e] = f2bf(f - bf2f(hi));
        }
        __syncthreads();
        #pragma unroll
        for (int rep = 0; rep < 2; rep++) {
            int c = rep * 256 + tid;
            int ct_loc = c >> 7, ke_loc = (c >> 6) & 1, lane = c & 63;
            int col = ct_loc * 16 + (lane & 15);
            int el  = ke_loc * 32 + (lane >> 4) * 8;
            int ct_g = m * 64 + h * 4 + ct_loc;
            int ke_g = (bx & 15) * 2 + ke_loc;
            size_t off = ((size_t)ct_g * 32 + ke_g) * 512 + (size_t)lane * 8;
            *(u16x8*)&wtp_h[off] = *(u16x8*)&Th[col][el];
            *(u16x8*)&wtp_l[off] = *(u16x8*)&Tl[col][el];
        }
    } else {
        // ---- Wo -> packed-frag wop ----
        int c = (bid - 4096 - 768) * 256 + tid;   // 0..131071
        int lane = c & 63, ke = (c >> 6) & 31, ct = c >> 11;
        int row = ct * 16 + (lane & 15);
        int e   = ke * 32 + (lane >> 4) * 8;
        const float* src = &Wo[(size_t)row * E_DIM + e];
        float4 f0 = *(const float4*)&src[0];
        float4 f1 = *(const float4*)&src[4];
        float fv[8] = {f0.x, f0.y, f0.z, f0.w, f1.x, f1.y, f1.z, f1.w};
        u16x8 hv;
        #pragma unroll
        for (int j = 0; j < 8; j++) hv[j] = f2bf(fv[j]);
        *(u16x8*)&wop[(size_t)c * 8] = hv;
    }
}

// ---------------------------------------------------------------------------
// Fused QKV GEMM, 128x128 tiles, BK=32. q/k: 3-term hi/lo; v: 1-term
// (needs only ~0.4% accuracy; saves 22% of kernel MFMA work). With 768
// blocks = exactly 3/CU round-robin, each CU gets one q, one k, one v block.
// q pre-scaled by log2(e)/sqrt(T) so attention softmax runs in exp2 domain.
// ---------------------------------------------------------------------------
__global__ __launch_bounds__(256, 3) void qkv_mfma_kernel(
    const u16* __restrict__ xh, const u16* __restrict__ xl,
    const u16* __restrict__ wtp_h, const u16* __restrict__ wtp_l,
    u16* __restrict__ qp_h, u16* __restrict__ qp_l,
    u16* __restrict__ kp_h, u16* __restrict__ kp_l,
    u16* __restrict__ vp)
{
    const int bx = blockIdx.x;         // 0..23: col-tile over 3072 packed cols
    const int r0 = blockIdx.y * 128;   // global row (b*T + t)
    const int m  = bx >> 3;            // 0=q 1=k 2=v
    const bool lo = (m != 2);

    __shared__ __align__(16) u16 SM[17408];
    u16* Ah = SM;             // 4096
    u16* Al = SM + 4096;      // 4096
    u16* Bh = SM + 8192;      // 4096
    u16* Bl = SM + 12288;     // 4096

    const int tid = threadIdx.x;
    const int w = tid >> 6, lane = tid & 63;
    const int qd = lane >> 4, n16 = lane & 15;
    const int wr = w >> 1, wc = w & 1;   // rows wr*64..+63, cols wc*64..+63

    f32x4 acc[4][4];
    #pragma unroll
    for (int i = 0; i < 4; i++)
        #pragma unroll
        for (int j = 0; j < 4; j++) acc[i][j] = (f32x4){0.f, 0.f, 0.f, 0.f};

    for (int k0 = 0; k0 < E_DIM; k0 += 32) {
        __syncthreads();
        const int ke = k0 >> 5;
        #pragma unroll
        for (int rep = 0; rep < 2; rep++) {
            int c = rep * 256 + tid;
            int mt = c >> 6;
            int cl = c & 63;
            int cn = cl & 15, cq = cl >> 4;
            size_t aoff = (size_t)(r0 + mt * 16 + cn) * E_DIM + k0 + cq * 8;
            gl_lds16(&xh[aoff], &Ah[c * 8]);
            if (lo) gl_lds16(&xl[aoff], &Al[c * 8]);
        }
        #pragma unroll
        for (int rep = 0; rep < 2; rep++) {
            int c = rep * 256 + tid;
            int ct_loc = c >> 6;
            int cl = c & 63;
            size_t boff = ((size_t)(bx * 8 + ct_loc) * 32 + ke) * 512 + (size_t)cl * 8;
            gl_lds16(&wtp_h[boff], &Bh[c * 8]);
            if (lo) gl_lds16(&wtp_l[boff], &Bl[c * 8]);
        }
        __syncthreads();

        bf16x8 ah[4], al_[4];
        #pragma unroll
        for (int i = 0; i < 4; i++) {
            ah[i] = *(bf16x8*)&Ah[((wr * 4 + i) * 64 + lane) * 8];
            if (lo) al_[i] = *(bf16x8*)&Al[((wr * 4 + i) * 64 + lane) * 8];
        }
        #pragma unroll
        for (int j = 0; j < 4; j++) {
            bf16x8 bh = *(bf16x8*)&Bh[((wc * 4 + j) * 64 + lane) * 8];
            if (lo) {
                bf16x8 bl = *(bf16x8*)&Bl[((wc * 4 + j) * 64 + lane) * 8];
                #pragma unroll
                for (int i = 0; i < 4; i++) {
                    acc[i][j] = MFMA16(ah[i], bh, acc[i][j]);
                    acc[i][j] = MFMA16(al_[i], bh, acc[i][j]);
                    acc[i][j] = MFMA16(ah[i], bl, acc[i][j]);
                }
            } else {
                #pragma unroll
                for (int i = 0; i < 4; i++)
                    acc[i][j] = MFMA16(ah[i], bh, acc[i][j]);
            }
        }
    }

    const int b  = r0 >> 11;
    const int tloc0 = r0 & 2047;

    if (m == 2) {
        const int h0 = (bx & 7) * 2;
        __syncthreads();
        const int VS = 136;
        u16* TR = SM + wc * 8704;
        #pragma unroll
        for (int i = 0; i < 4; i++) {
            int tl = wr * 64 + i * 16 + qd * 4;
            #pragma unroll
            for (int j = 0; j < 4; j++) {
                int d = j * 16 + n16;
                u16x4 pv;
                #pragma unroll
                for (int r = 0; r < 4; r++) pv[r] = f2bf(acc[i][j][r]);
                *(u16x4*)&TR[d * VS + tl] = pv;
            }
        }
        __syncthreads();
        const int st_g0 = tloc0 >> 6;
        #pragma unroll
        for (int rep = 0; rep < 8; rep++) {
            int c = rep * 256 + tid;
            int hh = c >> 10;
            int idx = c & 1023;
            int st_loc = idx >> 9, ks = (idx >> 8) & 1, dt = (idx >> 6) & 3, cl = idx & 63;
            int d  = dt * 16 + (cl & 15);
            int tl = st_loc * 64 + ks * 32 + (cl >> 4) * 8;
            u16x8 v8 = *(u16x8*)&SM[hh * 8704 + d * VS + tl];
            int hbv = (h0 + hh) * 2 + b;
            size_t off = ((((size_t)hbv * 32 + st_g0 + st_loc) * 2 + ks) * 4 + dt) * 512
                       + (size_t)cl * 8;
            *(u16x8*)&vp[off] = v8;
        }
    } else {
        const int h0 = (bx & 7) * 2;
        // q pre-scaled by log2(e)/sqrt(2048): softmax runs in exp2 domain
        const float sc = (m == 0) ? 0.031882937f : 1.0f;
        u16* oh = (m == 0) ? qp_h : kp_h;
        u16* ol = (m == 0) ? qp_l : kp_l;
        const int hb = (h0 + wc) * 2 + b;
        #pragma unroll
        for (int i = 0; i < 4; i++) {
            int nt = (tloc0 >> 4) + wr * 4 + i;
            #pragma unroll
            for (int j = 0; j < 4; j++) {
                int ks = j >> 1;
                int lp = (((j & 1) * 2 + (n16 >> 3)) << 4);
                int pos = n16 & 7;
                size_t cb = (((size_t)hb * 128 + nt) * 2 + ks) * 512;
                #pragma unroll
                for (int r = 0; r < 4; r++) {
                    float f = acc[i][j][r] * sc;
                    u16 hi = f2bf(f);
                    size_t o = cb + (size_t)(lp | (qd * 4 + r)) * 8 + pos;
                    oh[o] = hi;
                    ol[o] = f2bf(f - bf2f(hi));
                }
            }
        }
    }
}

// ---------------------------------------------------------------------------
// Flash attention (transposed): S^T = K Q^T ; O^T = V^T P^T.
// R10: K DOUBLE-BUFFERED with statically-unrolled x2 loop (compile-time
// disjoint buffers) -> ONE barrier per key-tile; K(st+1) DMA issued at the
// top of iter st with a full iteration to complete. exp2 softmax, trunc
// P-pack, conditional rescale, hb-major grid for XCD-L2 locality.
// ---------------------------------------------------------------------------
__global__ __launch_bounds__(256) void attn_kernel(
    const u16* __restrict__ qp_h, const u16* __restrict__ qp_l,
    const u16* __restrict__ kp_h, const u16* __restrict__ kp_l,
    const u16* __restrict__ vp, u16* __restrict__ attb)
{
    const int hb = blockIdx.x;       // 0..31 (= h*2 + b) — XCD = hb%8
    const int h = hb >> 1, b = hb & 1;
    const int t0 = blockIdx.y * 64;

    __shared__ __align__(16) u16 BKh0[4096], BKl0[4096];   // K buffer 0 (16KB)
    __shared__ __align__(16) u16 BKh1[4096], BKl1[4096];   // K buffer 1 (16KB)
    __shared__ __align__(16) u16 PT[4][16][72];            // 9KB, wave-private

    const int tid  = threadIdx.x;
    const int lane = tid & 63;
    const int w    = tid >> 6;
    const int qd   = lane >> 4;
    const int n16  = lane & 15;

    bf16x8 bqh[2], bql[2];
    {
        int qt = (t0 >> 4) + w;
        #pragma unroll
        for (int ks = 0; ks < 2; ks++) {
            size_t off = (((size_t)hb * 128 + qt) * 2 + ks) * 512 + (size_t)lane * 8;
            bqh[ks] = *(const bf16x8*)&qp_h[off];
            bql[ks] = *(const bf16x8*)&qp_l[off];
        }
    }

    f32x4 o4[4];
    #pragma unroll
    for (int dt = 0; dt < 4; dt++) o4[dt] = (f32x4){0.f, 0.f, 0.f, 0.f};
    float mr = -1e30f, lr = 0.f;

    // prologue: fill buffer 0 with K(0)
    {
        const size_t kb = (size_t)hb * 128 * 2 * 512;
        #pragma unroll
        for (int rep = 0; rep < 2; rep++) {
            int c = rep * 256 + tid;
            gl_lds16(&kp_h[kb + (size_t)c * 8], &BKh0[c * 8]);
            gl_lds16(&kp_l[kb + (size_t)c * 8], &BKl0[c * 8]);
        }
    }

    auto step = [&](int st, u16* RDh, u16* RDl, u16* WRh, u16* WRl) {
        __syncthreads();   // K(st) resident; WR buffer's prior readers done

        // issue K(st+1) DMA into the other buffer — full iteration to land
        if (st + 1 < T_LEN / 64) {
            const size_t kb = ((size_t)hb * 128 + (st + 1) * 4) * 2 * 512;
            #pragma unroll
            for (int rep = 0; rep < 2; rep++) {
                int c = rep * 256 + tid;
                gl_lds16(&kp_h[kb + (size_t)c * 8], &WRh[c * 8]);
                gl_lds16(&kp_l[kb + (size_t)c * 8], &WRl[c * 8]);
            }
        }

        // V(st) direct global->VGPR (consumed after softmax)
        bf16x8 av[4][2];
        #pragma unroll
        for (int ks = 0; ks < 2; ks++)
            #pragma unroll
            for (int dt = 0; dt < 4; dt++) {
                size_t off = ((((size_t)hb * 32 + st) * 2 + ks) * 4 + dt) * 512
                           + (size_t)lane * 8;
                av[dt][ks] = *(const bf16x8*)&vp[off];
            }

        // S^T = K Q^T, 3-term hi/lo, from the read buffer
        f32x4 s[4];
        #pragma unroll
        for (int c = 0; c < 4; c++) s[c] = (f32x4){0.f, 0.f, 0.f, 0.f};
        #pragma unroll
        for (int ks = 0; ks < 2; ks++) {
            #pragma unroll
            for (int c = 0; c < 4; c++) {
                bf16x8 akh = *(bf16x8*)&RDh[((c * 2 + ks) * 64 + lane) * 8];
                bf16x8 akl = *(bf16x8*)&RDl[((c * 2 + ks) * 64 + lane) * 8];
                s[c] = MFMA16(akh, bqh[ks], s[c]);
                s[c] = MFMA16(akh, bql[ks], s[c]);
                s[c] = MFMA16(akl, bqh[ks], s[c]);
            }
        }

        // online softmax in exp2 domain (query = lane column n16)
        float tmax = s[0][0];
        #pragma unroll
        for (int c = 0; c < 4; c++)
            #pragma unroll
            for (int r = 0; r < 4; r++) tmax = fmaxf(tmax, s[c][r]);
        tmax = fmaxf(tmax, __shfl_xor(tmax, 16));
        tmax = fmaxf(tmax, __shfl_xor(tmax, 32));
        float nm = fmaxf(mr, tmax);
        float al = __builtin_amdgcn_exp2f(mr - nm);   // == 1.0 iff max unchanged
        mr = nm;

        float psum = 0.f;
        #pragma unroll
        for (int c = 0; c < 4; c++) {
            float p0 = __builtin_amdgcn_exp2f(s[c][0] - nm);
            float p1 = __builtin_amdgcn_exp2f(s[c][1] - nm);
            float p2 = __builtin_amdgcn_exp2f(s[c][2] - nm);
            float p3 = __builtin_amdgcn_exp2f(s[c][3] - nm);
            psum += (p0 + p1) + (p2 + p3);
            u32x2 pk;   // truncating bf16 pack (P in [0,1], bias cancels)
            pk[0] = (__float_as_uint(p0) >> 16) | (__float_as_uint(p1) & 0xFFFF0000u);
            pk[1] = (__float_as_uint(p2) >> 16) | (__float_as_uint(p3) & 0xFFFF0000u);
            *(u32x2*)&PT[w][n16][c * 16 + qd * 4] = pk;
        }
        if (__any(al != 1.0f)) {
            lr *= al;
            #pragma unroll
            for (int dt = 0; dt < 4; dt++)
                #pragma unroll
                for (int r = 0; r < 4; r++) o4[dt][r] *= al;
        }
        lr += psum;

        // O^T += V^T P^T  (PT wave-private: no barrier)
        #pragma unroll
        for (int ks = 0; ks < 2; ks++) {
            bf16x8 bp = *(bf16x8*)&PT[w][n16][ks * 32 + qd * 8];
            #pragma unroll
            for (int dt = 0; dt < 4; dt++)
                o4[dt] = MFMA16(av[dt][ks], bp, o4[dt]);
        }
    };

    for (int i = 0; i < T_LEN / 128; i++) {
        step(2 * i,     BKh0, BKl0, BKh1, BKl1);
        step(2 * i + 1, BKh1, BKl1, BKh0, BKl0);
    }

    lr += __shfl_xor(lr, 16);
    lr += __shfl_xor(lr, 32);
    float inv = 1.f / lr;
    int row = t0 + w * 16 + n16;
    #pragma unroll
    for (int dt = 0; dt < 4; dt++) {
        u16x4 ov;
        #pragma unroll
        for (int r = 0; r < 4; r++) ov[r] = f2bf(o4[dt][r] * inv);
        *(u16x4*)&attb[(size_t)(b * T_LEN + row) * E_DIM + h * HD + dt * 16 + qd * 4] = ov;
    }
}

// ---------------------------------------------------------------------------
// Output projection: out(4096x1024 fp32) = attb(bf16) @ Wo^T.
// 128(M) x 64(N), BK=64, grid (16,32)=512 blocks. A staged; B direct packed.
// ---------------------------------------------------------------------------
__global__ __launch_bounds__(256) void outproj_mfma_kernel(
    const u16* __restrict__ attb, const u16* __restrict__ wop,
    float* __restrict__ out)
{
    const int c0 = blockIdx.x * 64;
    const int r0 = blockIdx.y * 128;

    __shared__ __align__(16) u16 As[8192];   // 16KB

    const int tid = threadIdx.x;
    const int w = tid >> 6, lane = tid & 63;
    const int qd = lane >> 4, n16 = lane & 15;
    const int wr = w >> 1, wc = w & 1;

    f32x4 acc[4][2];
    #pragma unroll
    for (int i = 0; i < 4; i++)
        #pragma unroll
        for (int j = 0; j < 2; j++) acc[i][j] = (f32x4){0.f, 0.f, 0.f, 0.f};

    for (int k0 = 0; k0 < E_DIM; k0 += 64) {
        __syncthreads();
        #pragma unroll
        for (int rep = 0; rep < 4; rep++) {
            int c = rep * 256 + tid;
            int mt = c >> 7, ks = (c >> 6) & 1;
            int cl = c & 63;
            int cn = cl & 15, cq = cl >> 4;
            gl_lds16(&attb[(size_t)(r0 + mt * 16 + cn) * E_DIM + k0 + ks * 32 + cq * 8],
                     &As[c * 8]);
        }
        bf16x8 bb[2][2];
        #pragma unroll
        for (int j = 0; j < 2; j++) {
            int ct = (c0 >> 4) + wc * 2 + j;
            #pragma unroll
            for (int ks = 0; ks < 2; ks++) {
                int ke = (k0 >> 5) + ks;
                bb[j][ks] = *(const bf16x8*)&wop[((size_t)ct * 32 + ke) * 512 + (size_t)lane * 8];
            }
        }
        __syncthreads();

        #pragma unroll
        for (int ks = 0; ks < 2; ks++) {
            bf16x8 a[4];
            #pragma unroll
            for (int i = 0; i < 4; i++)
                a[i] = *(bf16x8*)&As[(((wr * 4 + i) * 2 + ks) * 64 + lane) * 8];
            #pragma unroll
            for (int j = 0; j < 2; j++)
                #pragma unroll
                for (int i = 0; i < 4; i++)
                    acc[i][j] = MFMA16(a[i], bb[j][ks], acc[i][j]);
        }
    }

    #pragma unroll
    for (int i = 0; i < 4; i++) {
        #pragma unroll
        for (int r = 0; r < 4; r++) {
            int row = r0 + wr * 64 + i * 16 + qd * 4 + r;
            #pragma unroll
            for (int j = 0; j < 2; j++) {
                int col = c0 + wc * 32 + j * 16 + n16;
                out[(size_t)row * E_DIM + col] = acc[i][j][r];
            }
        }
    }
}

extern "C" void kernel_launch(void* const* d_in, const int* in_sizes, int n_in,
                              void* d_out, int out_size, void* d_ws, size_t ws_size,
                              hipStream_t stream)
{
    const float* x  = (const float*)d_in[0];
    const float* Wq = (const float*)d_in[1];
    const float* Wk = (const float*)d_in[2];
    const float* Wv = (const float*)d_in[3];
    const float* Wo = (const float*)d_in[4];
    float* out = (float*)d_out;

    const size_t NX = (size_t)4096 * 1024;
    const size_t NW = (size_t)3072 * 1024;
    const size_t NO = (size_t)1024 * 1024;
    const size_t NQ = (size_t)H_NUM * B_NUM * T_LEN * HD;

    u16* xh   = (u16*)d_ws;
    u16* xl   = xh + NX;
    u16* wtph = xl + NX;
    u16* wtpl = wtph + NW;
    u16* wop  = wtpl + NW;
    u16* qph  = wop + NO;
    u16* qpl  = qph + NQ;
    u16* kph  = qpl + NQ;
    u16* kpl  = kph + NQ;
    u16* vp   = kpl + NQ;
    u16* attb = xh;   // alias: xh dead after qkv_mfma

    convert_all_kernel<<<4096 + 768 + 512, 256, 0, stream>>>(
        x, Wq, Wk, Wv, Wo, xh, xl, wtph, wtpl, wop);

    dim3 g1(24, 32);
    qkv_mfma_kernel<<<g1, 256, 0, stream>>>(xh, xl, wtph, wtpl, qph, qpl, kph, kpl, vp);

    dim3 g2(H_NUM * B_NUM, T_LEN / 64);   // x = hb for XCD-L2 locality
    attn_kernel<<<g2, 256, 0, stream>>>(qph, qpl, kph, kpl, vp, attb);

    dim3 g3(E_DIM / 64, 4096 / 128);
    outproj_mfma_kernel<<<g3, 256, 0, stream>>>(attb, wop, out);
}